// Round 1
// baseline (865.089 us; speedup 1.0000x reference)
//
#include <hip/hip_runtime.h>

#define N_NODES 50000
#define N_EDGES 600000
#define D 128
#define H2 256
#define TN 16        // nodes per fused block (50000/16 = 3125 exactly)
#define NBKT 3125    // N_NODES / TN buckets
#define NB 64        // preprocessing blocks (600000/64 = 9375 exactly)
#define EPB 9375     // edges per preprocessing block
#define MAXC 2048    // perm chunk capacity in LDS (aliases s_hidden: 16KB = 2048 int2)

// ---------------------------------------------------------------------------
// Stage 1: per-block bucket histogram (LDS), written non-atomically to global.
// counts2d[b][bin] layout: [NB][NBKT].
__global__ __launch_bounds__(256) void count_kernel(const int* __restrict__ dst,
                                                    int* __restrict__ counts2d) {
    __shared__ int cnt[NBKT];   // 12.5 KB
    const int b = blockIdx.x, tid = threadIdx.x;
    for (int i = tid; i < NBKT; i += 256) cnt[i] = 0;
    __syncthreads();
    const int e0 = b * EPB;
    for (int i = tid; i < EPB; i += 256)
        atomicAdd(&cnt[dst[e0 + i] >> 4], 1);          // LDS atomic
    __syncthreads();
    for (int i = tid; i < NBKT; i += 256)
        counts2d[b * NBKT + i] = cnt[i];               // coalesced
}

// Stage 2a: per-bucket column prefix over blocks. thread = bucket.
// prefix2d[b][bin] = sum_{b'<b} counts2d[b'][bin]; totals[bin] = column sum.
__global__ __launch_bounds__(256) void colprefix_kernel(const int* __restrict__ counts2d,
                                                        int* __restrict__ prefix2d,
                                                        int* __restrict__ totals) {
    const int bin = blockIdx.x * 256 + threadIdx.x;
    if (bin >= NBKT) return;
    int s = 0;
    #pragma unroll 4
    for (int b = 0; b < NB; ++b) {
        const int r = counts2d[b * NBKT + bin];        // coalesced (lockstep b)
        prefix2d[b * NBKT + bin] = s;
        s += r;
    }
    totals[bin] = s;
}

// Stage 2b: exclusive scan of 3125 bucket totals -> offsets[3126]. One block.
__global__ __launch_bounds__(256) void bscan_kernel(const int* __restrict__ totals,
                                                    int* __restrict__ offsets) {
    __shared__ int wsum[4];
    __shared__ int carry_s;
    const int tid = threadIdx.x;
    const int lane = tid & 63;
    const int wv = tid >> 6;
    if (tid == 0) carry_s = 0;
    __syncthreads();
    for (int base = 0; base < NBKT; base += 256) {
        const int i = base + tid;
        const int cval = (i < NBKT) ? totals[i] : 0;
        int x = cval;
        #pragma unroll
        for (int d = 1; d < 64; d <<= 1) {
            int t = __shfl_up(x, d, 64);
            if (lane >= d) x += t;
        }
        if (lane == 63) wsum[wv] = x;
        __syncthreads();
        if (tid == 0) {
            int s = 0;
            #pragma unroll
            for (int w = 0; w < 4; ++w) { s += wsum[w]; wsum[w] = s; }
        }
        __syncthreads();
        const int carry = carry_s;
        const int prefix = carry + (wv > 0 ? wsum[wv - 1] : 0) + (x - cval);
        if (i < NBKT) offsets[i] = prefix;
        __syncthreads();                 // all reads of wsum/carry_s done
        if (tid == 0) carry_s = carry + wsum[3];
        __syncthreads();                 // update visible before next round
    }
    if (tid == 0) offsets[NBKT] = N_EDGES;
}

// Stage 3: scatter edges into bucket-grouped order via LDS cursors.
// Zero global atomics. Pack local node id (dst&15) into bits 20..23 of .x.
__global__ __launch_bounds__(256) void bscatter_kernel(const int* __restrict__ src,
                                                       const int* __restrict__ dst,
                                                       const int* __restrict__ offsets,
                                                       const int* __restrict__ prefix2d,
                                                       int2* __restrict__ perm2) {
    __shared__ int lcur[NBKT];  // 12.5 KB
    const int b = blockIdx.x, tid = threadIdx.x;
    for (int i = tid; i < NBKT; i += 256)
        lcur[i] = offsets[i] + prefix2d[b * NBKT + i];
    __syncthreads();
    const int e0 = b * EPB;
    for (int i = tid; i < EPB; i += 256) {
        const int e = e0 + i;
        const int d = dst[e];
        const int pos = atomicAdd(&lcur[d >> 4], 1);   // LDS atomic, returns old
        perm2[pos] = make_int2(e | ((d & (TN - 1)) << 20), src[e]);
    }
}

// ---------------------------------------------------------------------------
// Stage 4: fused gather + MLP + residual. Block = 16 nodes, 256 threads.
__global__ __launch_bounds__(256) void fused_kernel(
    const float* __restrict__ h, const float* __restrict__ ea,
    const int* __restrict__ offsets, const int2* __restrict__ perm2,
    const float* __restrict__ W1, const float* __restrict__ b1,
    const float* __restrict__ W2, const float* __restrict__ b2,
    const float* __restrict__ eps, float* __restrict__ out)
{
    __shared__ float s_aggr[TN][D];     // 8 KB
    __shared__ float s_hidden[TN][H2];  // 16 KB (phase A: aliased as perm staging)
    int2* s_perm = (int2*)&s_hidden[0][0];

    const int tid = threadIdx.x;

    // zero s_aggr
    for (int i = tid; i < TN * D / 4; i += 256)
        ((float4*)s_aggr)[i] = make_float4(0.f, 0.f, 0.f, 0.f);

    const int beg = offsets[blockIdx.x];
    const int end = offsets[blockIdx.x + 1];
    const int grp = tid >> 5;        // 0..7
    const int c = (tid & 31) << 2;   // float offset 0..124

    for (int cb = beg; cb < end; cb += MAXC) {
        const int cnt = min(end - cb, MAXC);
        __syncthreads();  // s_aggr zero done / prior s_perm use done
        for (int i = tid; i < cnt; i += 256) s_perm[i] = perm2[cb + i];
        __syncthreads();
        // contiguous sub-range per 32-lane group; buckets are unsorted in t,
        // so accumulate branchlessly with LDS float atomics, and software-
        // pipeline (depth 3: perm one stage ahead of its ea/h row loads).
        const int per = (cnt + 7) >> 3;
        const int lo = grp * per;
        const int hi = min(lo + per, cnt);
        if (lo < hi) {
            const int last = hi - 1;
            int2 p0 = s_perm[lo];
            int2 p1 = s_perm[min(lo + 1, last)];
            int2 p2 = s_perm[min(lo + 2, last)];
            float4 e0v = *(const float4*)(ea + (size_t)(p0.x & 0xFFFFF) * D + c);
            float4 h0v = *(const float4*)(h + (size_t)p0.y * D + c);
            float4 e1v = *(const float4*)(ea + (size_t)(p1.x & 0xFFFFF) * D + c);
            float4 h1v = *(const float4*)(h + (size_t)p1.y * D + c);
            #pragma unroll 2
            for (int j = lo; j < hi; ++j) {
                const int2 p3 = s_perm[min(j + 3, last)];
                const float4 e2v = *(const float4*)(ea + (size_t)(p2.x & 0xFFFFF) * D + c);
                const float4 h2v = *(const float4*)(h + (size_t)p2.y * D + c);
                const int t = p0.x >> 20;
                atomicAdd(&s_aggr[t][c + 0], e0v.x + h0v.x);
                atomicAdd(&s_aggr[t][c + 1], e0v.y + h0v.y);
                atomicAdd(&s_aggr[t][c + 2], e0v.z + h0v.z);
                atomicAdd(&s_aggr[t][c + 3], e0v.w + h0v.w);
                p0 = p1; e0v = e1v; h0v = h1v;
                p1 = p2; e1v = e2v; h1v = h2v;
                p2 = p3;
            }
        }
    }
    __syncthreads();  // aggr complete; s_perm (aliased with s_hidden) dead

    // ---- GEMM1: hidden = relu(aggr @ W1 + b1) ----
    {
        const int j0 = (tid & 63) << 2;    // 0..252
        const int tbase = (tid >> 6) << 2; // 0,4,8,12
        float4 acc1[4];
        const float4 bv = *(const float4*)(b1 + j0);
        #pragma unroll
        for (int t = 0; t < 4; ++t) acc1[t] = bv;
        for (int k = 0; k < D; k += 4) {
            float4 w[4];
            #pragma unroll
            for (int q = 0; q < 4; ++q)
                w[q] = *(const float4*)(W1 + (size_t)(k + q) * H2 + j0);
            #pragma unroll
            for (int t = 0; t < 4; ++t) {
                const float4 a = *(const float4*)&s_aggr[tbase + t][k];
                acc1[t].x = fmaf(a.x, w[0].x, acc1[t].x);
                acc1[t].y = fmaf(a.x, w[0].y, acc1[t].y);
                acc1[t].z = fmaf(a.x, w[0].z, acc1[t].z);
                acc1[t].w = fmaf(a.x, w[0].w, acc1[t].w);
                acc1[t].x = fmaf(a.y, w[1].x, acc1[t].x);
                acc1[t].y = fmaf(a.y, w[1].y, acc1[t].y);
                acc1[t].z = fmaf(a.y, w[1].z, acc1[t].z);
                acc1[t].w = fmaf(a.y, w[1].w, acc1[t].w);
                acc1[t].x = fmaf(a.z, w[2].x, acc1[t].x);
                acc1[t].y = fmaf(a.z, w[2].y, acc1[t].y);
                acc1[t].z = fmaf(a.z, w[2].z, acc1[t].z);
                acc1[t].w = fmaf(a.z, w[2].w, acc1[t].w);
                acc1[t].x = fmaf(a.w, w[3].x, acc1[t].x);
                acc1[t].y = fmaf(a.w, w[3].y, acc1[t].y);
                acc1[t].z = fmaf(a.w, w[3].z, acc1[t].z);
                acc1[t].w = fmaf(a.w, w[3].w, acc1[t].w);
            }
        }
        #pragma unroll
        for (int t = 0; t < 4; ++t) {
            float4 r;
            r.x = fmaxf(acc1[t].x, 0.f);
            r.y = fmaxf(acc1[t].y, 0.f);
            r.z = fmaxf(acc1[t].z, 0.f);
            r.w = fmaxf(acc1[t].w, 0.f);
            *(float4*)&s_hidden[tbase + t][j0] = r;
        }
    }
    __syncthreads();

    // ---- GEMM2 + residual ----
    {
        const int i0 = (tid & 31) << 2;    // 0..124
        const int g = tid >> 5;            // 0..7 -> nodes g, g+8
        float4 acc2[2];
        const float4 bv = *(const float4*)(b2 + i0);
        acc2[0] = bv; acc2[1] = bv;
        for (int k = 0; k < H2; k += 4) {
            float4 w[4];
            #pragma unroll
            for (int q = 0; q < 4; ++q)
                w[q] = *(const float4*)(W2 + (size_t)(k + q) * D + i0);
            #pragma unroll
            for (int u = 0; u < 2; ++u) {
                const float4 a = *(const float4*)&s_hidden[g + u * 8][k];
                acc2[u].x = fmaf(a.x, w[0].x, acc2[u].x);
                acc2[u].y = fmaf(a.x, w[0].y, acc2[u].y);
                acc2[u].z = fmaf(a.x, w[0].z, acc2[u].z);
                acc2[u].w = fmaf(a.x, w[0].w, acc2[u].w);
                acc2[u].x = fmaf(a.y, w[1].x, acc2[u].x);
                acc2[u].y = fmaf(a.y, w[1].y, acc2[u].y);
                acc2[u].z = fmaf(a.y, w[1].z, acc2[u].z);
                acc2[u].w = fmaf(a.y, w[1].w, acc2[u].w);
                acc2[u].x = fmaf(a.z, w[2].x, acc2[u].x);
                acc2[u].y = fmaf(a.z, w[2].y, acc2[u].y);
                acc2[u].z = fmaf(a.z, w[2].z, acc2[u].z);
                acc2[u].w = fmaf(a.z, w[2].w, acc2[u].w);
                acc2[u].x = fmaf(a.w, w[3].x, acc2[u].x);
                acc2[u].y = fmaf(a.w, w[3].y, acc2[u].y);
                acc2[u].z = fmaf(a.w, w[3].z, acc2[u].z);
                acc2[u].w = fmaf(a.w, w[3].w, acc2[u].w);
            }
        }
        const float ep = 1.0f + eps[0];
        #pragma unroll
        for (int u = 0; u < 2; ++u) {
            const int node = blockIdx.x * TN + g + u * 8;
            const float4 hv = *(const float4*)(h + (size_t)node * D + i0);
            float4 o;
            o.x = fmaf(ep, hv.x, acc2[u].x);
            o.y = fmaf(ep, hv.y, acc2[u].y);
            o.z = fmaf(ep, hv.z, acc2[u].z);
            o.w = fmaf(ep, hv.w, acc2[u].w);
            *(float4*)(out + (size_t)node * D + i0) = o;
        }
    }
}

extern "C" void kernel_launch(void* const* d_in, const int* in_sizes, int n_in,
                              void* d_out, int out_size, void* d_ws, size_t ws_size,
                              hipStream_t stream) {
    const float* h   = (const float*)d_in[0];
    const float* ea  = (const float*)d_in[1];
    const int*   src = (const int*)d_in[2];
    const int*   dst = (const int*)d_in[3];
    const float* W1  = (const float*)d_in[4];
    const float* b1  = (const float*)d_in[5];
    const float* W2  = (const float*)d_in[6];
    const float* b2  = (const float*)d_in[7];
    const float* eps = (const float*)d_in[8];
    float* out = (float*)d_out;

    // Workspace layout (5.63 MB total; counts2d aliases perm2 -- counts2d is
    // dead after colprefix, perm2 first written in bscatter, stream-ordered):
    char* ws = (char*)d_ws;
    int2* perm2    = (int2*)ws;                    // 4,800,000 B
    int*  counts2d = (int*)ws;                     //   800,000 B (alias, dead early)
    int*  prefix2d = (int*)(ws + 4800000);         //   800,000 B
    int*  totals   = (int*)(ws + 5600000);         //    12,500 B
    int*  offsets  = (int*)(ws + 5612544);         //    12,504 B (3126 ints)

    count_kernel    <<<NB, 256, 0, stream>>>(dst, counts2d);
    colprefix_kernel<<<(NBKT + 255) / 256, 256, 0, stream>>>(counts2d, prefix2d, totals);
    bscan_kernel    <<<1, 256, 0, stream>>>(totals, offsets);
    bscatter_kernel <<<NB, 256, 0, stream>>>(src, dst, offsets, prefix2d, perm2);
    fused_kernel    <<<NBKT, 256, 0, stream>>>(
        h, ea, offsets, perm2, W1, b1, W2, b2, eps, out);
}

// Round 2
// 670.990 us; speedup vs baseline: 1.2893x; 1.2893x over previous
//
#include <hip/hip_runtime.h>

#define N_NODES 50000
#define N_EDGES 600000
#define D 128
#define H2 256
#define TN 16      // nodes per fused block (50000/16 = 3125 exactly)

// ---------------------------------------------------------------------------
// Stage 1: histogram of dst -> counts[50000]
__global__ __launch_bounds__(256) void hist_kernel(const int* __restrict__ dst,
                                                   int* __restrict__ counts) {
    unsigned int e = blockIdx.x * 256u + threadIdx.x;
    if (e < N_EDGES) atomicAdd(&counts[dst[e]], 1);
}

// Stage 2a: block-local exclusive scan (196 blocks x 256 threads)
__global__ __launch_bounds__(256) void scan1_kernel(const int* __restrict__ counts,
                                                    int* __restrict__ scanned,
                                                    int* __restrict__ blocksums) {
    __shared__ int wsum[4];
    const int tid = threadIdx.x;
    const int lane = tid & 63;
    const int wv = tid >> 6;
    const int i = blockIdx.x * 256 + tid;
    const int cval = (i < N_NODES) ? counts[i] : 0;
    int x = cval;
    #pragma unroll
    for (int d = 1; d < 64; d <<= 1) {
        int t = __shfl_up(x, d, 64);
        if (lane >= d) x += t;
    }
    if (lane == 63) wsum[wv] = x;
    __syncthreads();
    if (tid == 0) {
        int s = 0;
        #pragma unroll
        for (int w = 0; w < 4; ++w) { s += wsum[w]; wsum[w] = s; }
    }
    __syncthreads();
    const int prefix = (wv > 0 ? wsum[wv - 1] : 0) + (x - cval);
    if (i < N_NODES) scanned[i] = prefix;
    if (tid == 0) blocksums[blockIdx.x] = wsum[3];
}

// Stage 2b: exclusive scan of the 196 block sums (1 block, 256 threads)
__global__ __launch_bounds__(256) void scan2_kernel(const int* __restrict__ blocksums,
                                                    int* __restrict__ blockbase, int nb) {
    __shared__ int wsum[4];
    const int tid = threadIdx.x;
    const int lane = tid & 63;
    const int wv = tid >> 6;
    const int cval = (tid < nb) ? blocksums[tid] : 0;
    int x = cval;
    #pragma unroll
    for (int d = 1; d < 64; d <<= 1) {
        int t = __shfl_up(x, d, 64);
        if (lane >= d) x += t;
    }
    if (lane == 63) wsum[wv] = x;
    __syncthreads();
    if (tid == 0) {
        int s = 0;
        #pragma unroll
        for (int w = 0; w < 4; ++w) { s += wsum[w]; wsum[w] = s; }
    }
    __syncthreads();
    if (tid < nb) blockbase[tid] = (wv > 0 ? wsum[wv - 1] : 0) + (x - cval);
}

// Stage 2c: add block bases -> offsets, prime cursor
__global__ __launch_bounds__(256) void scan3_kernel(const int* __restrict__ scanned,
                                                    const int* __restrict__ blockbase,
                                                    int* __restrict__ offsets,
                                                    int* __restrict__ cursor) {
    const int i = blockIdx.x * 256 + threadIdx.x;
    if (i < N_NODES) {
        const int v = scanned[i] + blockbase[blockIdx.x];
        offsets[i] = v;
        cursor[i] = v;
    }
    if (i == 0) offsets[N_NODES] = N_EDGES;
}

// Stage 3: scatter edges into dst-sorted order. perm2[p] = (edge_id, src).
__global__ __launch_bounds__(256) void scatter_kernel(const int* __restrict__ src,
                                                      const int* __restrict__ dst,
                                                      int* __restrict__ cursor,
                                                      int2* __restrict__ perm2) {
    unsigned int e = blockIdx.x * 256u + threadIdx.x;
    if (e >= N_EDGES) return;
    const int d = dst[e];
    const int p = atomicAdd(&cursor[d], 1);
    perm2[p] = make_int2((int)e, src[e]);
}

// ---------------------------------------------------------------------------
// Stage 4: fused gather + MLP + residual. Block = 16 nodes, 256 threads.
// Gather decomposition: 16 threads own one node (thread-private accumulator,
// branchless inner loop, 4 independent float4 loads per edge -> deep MLP).
// LDS: s_hidden[16][256] (16 KB); s_aggr[16][128] aliases its first half
// (aggr is dead once GEMM1's k-loop completes, before s_hidden is written).
__global__ __launch_bounds__(256) void fused_kernel(
    const float* __restrict__ h, const float* __restrict__ ea,
    const int* __restrict__ offsets, const int2* __restrict__ perm2,
    const float* __restrict__ W1, const float* __restrict__ b1,
    const float* __restrict__ W2, const float* __restrict__ b2,
    const float* __restrict__ eps, float* __restrict__ out)
{
    __shared__ float s_lds[TN * H2];   // 16 KB
    // s_aggr  : s_lds[i*D + k],   i<16, k<128  (first 8 KB)
    // s_hidden: s_lds[i*H2 + j],  i<16, j<256  (all 16 KB)

    const int tid = threadIdx.x;

    // ---- gather: 16-lane subgroup per node, register accumulation ----
    {
        const int t  = tid >> 4;            // node 0..15
        const int c8 = (tid & 15) << 3;     // float col 0..120 (8 per lane)
        const int node = blockIdx.x * TN + t;
        const int beg = offsets[node];
        const int end = offsets[node + 1];
        float4 a0 = make_float4(0.f, 0.f, 0.f, 0.f);
        float4 a1 = make_float4(0.f, 0.f, 0.f, 0.f);
        if (beg < end) {
            int2 p = perm2[beg];            // broadcast within subgroup
            for (int j = beg; j < end; ++j) {
                const int2 pn = (j + 1 < end) ? perm2[j + 1] : p;
                const float* er = ea + (size_t)p.x * D + c8;
                const float* hr = h  + (size_t)p.y * D + c8;
                const float4 e0 = *(const float4*)(er);
                const float4 e1 = *(const float4*)(er + 4);
                const float4 h0 = *(const float4*)(hr);
                const float4 h1 = *(const float4*)(hr + 4);
                a0.x += e0.x + h0.x;
                a0.y += e0.y + h0.y;
                a0.z += e0.z + h0.z;
                a0.w += e0.w + h0.w;
                a1.x += e1.x + h1.x;
                a1.y += e1.y + h1.y;
                a1.z += e1.z + h1.z;
                a1.w += e1.w + h1.w;
                p = pn;
            }
        }
        *(float4*)&s_lds[t * D + c8]     = a0;
        *(float4*)&s_lds[t * D + c8 + 4] = a1;
    }
    __syncthreads();

    // ---- GEMM1: hidden = relu(aggr @ W1 + b1) ----
    {
        const int j0 = (tid & 63) << 2;    // 0..252
        const int tbase = (tid >> 6) << 2; // 0,4,8,12
        float4 acc1[4];
        const float4 bv = *(const float4*)(b1 + j0);
        #pragma unroll
        for (int t = 0; t < 4; ++t) acc1[t] = bv;
        for (int k = 0; k < D; k += 4) {
            float4 w[4];
            #pragma unroll
            for (int q = 0; q < 4; ++q)
                w[q] = *(const float4*)(W1 + (size_t)(k + q) * H2 + j0);
            #pragma unroll
            for (int t = 0; t < 4; ++t) {
                const float4 a = *(const float4*)&s_lds[(tbase + t) * D + k];
                acc1[t].x = fmaf(a.x, w[0].x, acc1[t].x);
                acc1[t].y = fmaf(a.x, w[0].y, acc1[t].y);
                acc1[t].z = fmaf(a.x, w[0].z, acc1[t].z);
                acc1[t].w = fmaf(a.x, w[0].w, acc1[t].w);
                acc1[t].x = fmaf(a.y, w[1].x, acc1[t].x);
                acc1[t].y = fmaf(a.y, w[1].y, acc1[t].y);
                acc1[t].z = fmaf(a.y, w[1].z, acc1[t].z);
                acc1[t].w = fmaf(a.y, w[1].w, acc1[t].w);
                acc1[t].x = fmaf(a.z, w[2].x, acc1[t].x);
                acc1[t].y = fmaf(a.z, w[2].y, acc1[t].y);
                acc1[t].z = fmaf(a.z, w[2].z, acc1[t].z);
                acc1[t].w = fmaf(a.z, w[2].w, acc1[t].w);
                acc1[t].x = fmaf(a.w, w[3].x, acc1[t].x);
                acc1[t].y = fmaf(a.w, w[3].y, acc1[t].y);
                acc1[t].z = fmaf(a.w, w[3].z, acc1[t].z);
                acc1[t].w = fmaf(a.w, w[3].w, acc1[t].w);
            }
        }
        __syncthreads();  // all s_aggr reads done before s_hidden overwrites
        #pragma unroll
        for (int t = 0; t < 4; ++t) {
            float4 r;
            r.x = fmaxf(acc1[t].x, 0.f);
            r.y = fmaxf(acc1[t].y, 0.f);
            r.z = fmaxf(acc1[t].z, 0.f);
            r.w = fmaxf(acc1[t].w, 0.f);
            *(float4*)&s_lds[(tbase + t) * H2 + j0] = r;
        }
    }
    __syncthreads();

    // ---- GEMM2 + residual ----
    {
        const int i0 = (tid & 31) << 2;    // 0..124
        const int g = tid >> 5;            // 0..7 -> nodes g, g+8
        float4 acc2[2];
        const float4 bv = *(const float4*)(b2 + i0);
        acc2[0] = bv; acc2[1] = bv;
        for (int k = 0; k < H2; k += 4) {
            float4 w[4];
            #pragma unroll
            for (int q = 0; q < 4; ++q)
                w[q] = *(const float4*)(W2 + (size_t)(k + q) * D + i0);
            #pragma unroll
            for (int u = 0; u < 2; ++u) {
                const float4 a = *(const float4*)&s_lds[(g + u * 8) * H2 + k];
                acc2[u].x = fmaf(a.x, w[0].x, acc2[u].x);
                acc2[u].y = fmaf(a.x, w[0].y, acc2[u].y);
                acc2[u].z = fmaf(a.x, w[0].z, acc2[u].z);
                acc2[u].w = fmaf(a.x, w[0].w, acc2[u].w);
                acc2[u].x = fmaf(a.y, w[1].x, acc2[u].x);
                acc2[u].y = fmaf(a.y, w[1].y, acc2[u].y);
                acc2[u].z = fmaf(a.y, w[1].z, acc2[u].z);
                acc2[u].w = fmaf(a.y, w[1].w, acc2[u].w);
                acc2[u].x = fmaf(a.z, w[2].x, acc2[u].x);
                acc2[u].y = fmaf(a.z, w[2].y, acc2[u].y);
                acc2[u].z = fmaf(a.z, w[2].z, acc2[u].z);
                acc2[u].w = fmaf(a.z, w[2].w, acc2[u].w);
                acc2[u].x = fmaf(a.w, w[3].x, acc2[u].x);
                acc2[u].y = fmaf(a.w, w[3].y, acc2[u].y);
                acc2[u].z = fmaf(a.w, w[3].z, acc2[u].z);
                acc2[u].w = fmaf(a.w, w[3].w, acc2[u].w);
            }
        }
        const float ep = 1.0f + eps[0];
        #pragma unroll
        for (int u = 0; u < 2; ++u) {
            const int node = blockIdx.x * TN + g + u * 8;
            const float4 hv = *(const float4*)(h + (size_t)node * D + i0);
            float4 o;
            o.x = fmaf(ep, hv.x, acc2[u].x);
            o.y = fmaf(ep, hv.y, acc2[u].y);
            o.z = fmaf(ep, hv.z, acc2[u].z);
            o.w = fmaf(ep, hv.w, acc2[u].w);
            *(float4*)(out + (size_t)node * D + i0) = o;
        }
    }
}

extern "C" void kernel_launch(void* const* d_in, const int* in_sizes, int n_in,
                              void* d_out, int out_size, void* d_ws, size_t ws_size,
                              hipStream_t stream) {
    const float* h   = (const float*)d_in[0];
    const float* ea  = (const float*)d_in[1];
    const int*   src = (const int*)d_in[2];
    const int*   dst = (const int*)d_in[3];
    const float* W1  = (const float*)d_in[4];
    const float* b1  = (const float*)d_in[5];
    const float* W2  = (const float*)d_in[6];
    const float* b2  = (const float*)d_in[7];
    const float* eps = (const float*)d_in[8];
    float* out = (float*)d_out;

    char* ws = (char*)d_ws;
    int*  counts    = (int*)ws;                    // 200 KB
    int*  scanned   = (int*)(ws + 256 * 1024);     // 200 KB
    int*  offsets   = (int*)(ws + 512 * 1024);     // 200 KB (+1)
    int*  cursor    = (int*)(ws + 768 * 1024);     // 200 KB
    int*  blocksums = (int*)(ws + 1008 * 1024);    // 1 KB
    int*  blockbase = (int*)(ws + 1012 * 1024);    // 1 KB
    int2* perm2     = (int2*)(ws + 1024 * 1024);   // 4.8 MB

    hipMemsetAsync(counts, 0, N_NODES * sizeof(int), stream);

    const int eblocks = (N_EDGES + 255) / 256;     // 2344
    const int nblocks = (N_NODES + 255) / 256;     // 196

    hist_kernel<<<eblocks, 256, 0, stream>>>(dst, counts);
    scan1_kernel<<<nblocks, 256, 0, stream>>>(counts, scanned, blocksums);
    scan2_kernel<<<1, 256, 0, stream>>>(blocksums, blockbase, nblocks);
    scan3_kernel<<<nblocks, 256, 0, stream>>>(scanned, blockbase, offsets, cursor);
    scatter_kernel<<<eblocks, 256, 0, stream>>>(src, dst, cursor, perm2);
    fused_kernel<<<N_NODES / TN, 256, 0, stream>>>(
        h, ea, offsets, perm2, W1, b1, W2, b2, eps, out);
}

// Round 3
// 656.388 us; speedup vs baseline: 1.3180x; 1.0222x over previous
//
#include <hip/hip_runtime.h>

#define N_NODES 50000
#define N_EDGES 600000
#define D 128
#define H2 256
#define TN 16      // nodes per fused block (50000/16 = 3125 exactly)
#define MAXC 2048  // perm chunk capacity in LDS (16KB = 2048 int2)

typedef float f4 __attribute__((ext_vector_type(4)));

__device__ __forceinline__ f4 ldg_nt(const float* p) {
    return __builtin_nontemporal_load((const f4*)p);
}
__device__ __forceinline__ f4 ldg(const float* p) {
    return *(const f4*)p;
}

// ---------------------------------------------------------------------------
// Stage 1: histogram of dst -> counts[50000]
__global__ __launch_bounds__(256) void hist_kernel(const int* __restrict__ dst,
                                                   int* __restrict__ counts) {
    unsigned int e = blockIdx.x * 256u + threadIdx.x;
    if (e < N_EDGES) atomicAdd(&counts[dst[e]], 1);
}

// Stage 2a: block-local exclusive scan (196 blocks x 256 threads)
__global__ __launch_bounds__(256) void scan1_kernel(const int* __restrict__ counts,
                                                    int* __restrict__ scanned,
                                                    int* __restrict__ blocksums) {
    __shared__ int wsum[4];
    const int tid = threadIdx.x;
    const int lane = tid & 63;
    const int wv = tid >> 6;
    const int i = blockIdx.x * 256 + tid;
    const int cval = (i < N_NODES) ? counts[i] : 0;
    int x = cval;
    #pragma unroll
    for (int d = 1; d < 64; d <<= 1) {
        int t = __shfl_up(x, d, 64);
        if (lane >= d) x += t;
    }
    if (lane == 63) wsum[wv] = x;
    __syncthreads();
    if (tid == 0) {
        int s = 0;
        #pragma unroll
        for (int w = 0; w < 4; ++w) { s += wsum[w]; wsum[w] = s; }
    }
    __syncthreads();
    const int prefix = (wv > 0 ? wsum[wv - 1] : 0) + (x - cval);
    if (i < N_NODES) scanned[i] = prefix;
    if (tid == 0) blocksums[blockIdx.x] = wsum[3];
}

// Stage 2b: exclusive scan of the 196 block sums (1 block, 256 threads)
__global__ __launch_bounds__(256) void scan2_kernel(const int* __restrict__ blocksums,
                                                    int* __restrict__ blockbase, int nb) {
    __shared__ int wsum[4];
    const int tid = threadIdx.x;
    const int lane = tid & 63;
    const int wv = tid >> 6;
    const int cval = (tid < nb) ? blocksums[tid] : 0;
    int x = cval;
    #pragma unroll
    for (int d = 1; d < 64; d <<= 1) {
        int t = __shfl_up(x, d, 64);
        if (lane >= d) x += t;
    }
    if (lane == 63) wsum[wv] = x;
    __syncthreads();
    if (tid == 0) {
        int s = 0;
        #pragma unroll
        for (int w = 0; w < 4; ++w) { s += wsum[w]; wsum[w] = s; }
    }
    __syncthreads();
    if (tid < nb) blockbase[tid] = (wv > 0 ? wsum[wv - 1] : 0) + (x - cval);
}

// Stage 2c: add block bases -> offsets, prime cursor
__global__ __launch_bounds__(256) void scan3_kernel(const int* __restrict__ scanned,
                                                    const int* __restrict__ blockbase,
                                                    int* __restrict__ offsets,
                                                    int* __restrict__ cursor) {
    const int i = blockIdx.x * 256 + threadIdx.x;
    if (i < N_NODES) {
        const int v = scanned[i] + blockbase[blockIdx.x];
        offsets[i] = v;
        cursor[i] = v;
    }
    if (i == 0) offsets[N_NODES] = N_EDGES;
}

// Stage 3: scatter edges into dst-sorted order. perm2[p] = (edge_id, src).
__global__ __launch_bounds__(256) void scatter_kernel(const int* __restrict__ src,
                                                      const int* __restrict__ dst,
                                                      int* __restrict__ cursor,
                                                      int2* __restrict__ perm2) {
    unsigned int e = blockIdx.x * 256u + threadIdx.x;
    if (e >= N_EDGES) return;
    const int d = dst[e];
    const int p = atomicAdd(&cursor[d], 1);
    perm2[p] = make_int2((int)e, src[e]);
}

// ---------------------------------------------------------------------------
// Stage 4: fused gather + MLP + residual. Block = 16 nodes, 256 threads.
// Gather: 16-lane subgroup per node, thread-private register accumulators,
// perm chunk staged in LDS, 4-edge unroll => 16 independent row-load
// instructions (16KB/wave) in flight per iteration. ea loads non-temporal
// (read-once; keep h cache-resident). LDS (16KB) is time-shared:
//   phase A: s_perm (2048 int2) ; phase B: aggr[16][128] ; phase C: hidden[16][256]
__global__ __launch_bounds__(256, 4) void fused_kernel(
    const float* __restrict__ h, const float* __restrict__ ea,
    const int* __restrict__ offsets, const int2* __restrict__ perm2,
    const float* __restrict__ W1, const float* __restrict__ b1,
    const float* __restrict__ W2, const float* __restrict__ b2,
    const float* __restrict__ eps, float* __restrict__ out)
{
    __shared__ float s_lds[TN * H2];   // 16 KB
    int2* s_perm = (int2*)s_lds;

    const int tid = threadIdx.x;
    const int t  = tid >> 4;            // node 0..15
    const int c8 = (tid & 15) << 3;     // float col 0..120 (8 per lane)
    const int node0 = blockIdx.x * TN;
    const int blkbeg = offsets[node0];
    const int blkend = offsets[node0 + TN];
    const int nbeg = offsets[node0 + t];
    const int nend = offsets[node0 + t + 1];

    f4 a0 = (f4)(0.f);
    f4 a1 = (f4)(0.f);

    for (int cb = blkbeg; cb < blkend; cb += MAXC) {
        const int cnt = min(blkend - cb, MAXC);
        __syncthreads();   // prior chunk's s_perm reads done
        for (int i = tid; i < cnt; i += 256) s_perm[i] = perm2[cb + i];
        __syncthreads();
        const int lo = max(nbeg - cb, 0);
        const int hi = min(nend - cb, cnt);
        int j = lo;
        // main: 4 edges per iteration, loads fully hoisted (16 VMEM in flight)
        for (; j + 3 < hi; j += 4) {
            int2 p[4];
            #pragma unroll
            for (int q = 0; q < 4; ++q) p[q] = s_perm[j + q];
            f4 ev0[4], ev1[4], hv0[4], hv1[4];
            #pragma unroll
            for (int q = 0; q < 4; ++q) {
                const float* er = ea + (size_t)p[q].x * D + c8;
                const float* hr = h  + (size_t)p[q].y * D + c8;
                ev0[q] = ldg_nt(er);
                ev1[q] = ldg_nt(er + 4);
                hv0[q] = ldg(hr);
                hv1[q] = ldg(hr + 4);
            }
            #pragma unroll
            for (int q = 0; q < 4; ++q) {
                a0 += ev0[q] + hv0[q];
                a1 += ev1[q] + hv1[q];
            }
        }
        // tail: 0..3 edges
        for (; j < hi; ++j) {
            const int2 p = s_perm[j];
            const float* er = ea + (size_t)p.x * D + c8;
            const float* hr = h  + (size_t)p.y * D + c8;
            a0 += ldg_nt(er)     + ldg(hr);
            a1 += ldg_nt(er + 4) + ldg(hr + 4);
        }
    }
    __syncthreads();   // all s_perm reads done before aggr overwrites
    *(f4*)&s_lds[t * D + c8]     = a0;
    *(f4*)&s_lds[t * D + c8 + 4] = a1;
    __syncthreads();

    // ---- GEMM1: hidden = relu(aggr @ W1 + b1) ----
    {
        const int j0 = (tid & 63) << 2;    // 0..252
        const int tbase = (tid >> 6) << 2; // 0,4,8,12
        float4 acc1[4];
        const float4 bv = *(const float4*)(b1 + j0);
        #pragma unroll
        for (int q = 0; q < 4; ++q) acc1[q] = bv;
        for (int k = 0; k < D; k += 4) {
            float4 w[4];
            #pragma unroll
            for (int q = 0; q < 4; ++q)
                w[q] = *(const float4*)(W1 + (size_t)(k + q) * H2 + j0);
            #pragma unroll
            for (int u = 0; u < 4; ++u) {
                const float4 a = *(const float4*)&s_lds[(tbase + u) * D + k];
                acc1[u].x = fmaf(a.x, w[0].x, acc1[u].x);
                acc1[u].y = fmaf(a.x, w[0].y, acc1[u].y);
                acc1[u].z = fmaf(a.x, w[0].z, acc1[u].z);
                acc1[u].w = fmaf(a.x, w[0].w, acc1[u].w);
                acc1[u].x = fmaf(a.y, w[1].x, acc1[u].x);
                acc1[u].y = fmaf(a.y, w[1].y, acc1[u].y);
                acc1[u].z = fmaf(a.y, w[1].z, acc1[u].z);
                acc1[u].w = fmaf(a.y, w[1].w, acc1[u].w);
                acc1[u].x = fmaf(a.z, w[2].x, acc1[u].x);
                acc1[u].y = fmaf(a.z, w[2].y, acc1[u].y);
                acc1[u].z = fmaf(a.z, w[2].z, acc1[u].z);
                acc1[u].w = fmaf(a.z, w[2].w, acc1[u].w);
                acc1[u].x = fmaf(a.w, w[3].x, acc1[u].x);
                acc1[u].y = fmaf(a.w, w[3].y, acc1[u].y);
                acc1[u].z = fmaf(a.w, w[3].z, acc1[u].z);
                acc1[u].w = fmaf(a.w, w[3].w, acc1[u].w);
            }
        }
        __syncthreads();  // all aggr reads done before hidden overwrites
        #pragma unroll
        for (int u = 0; u < 4; ++u) {
            float4 r;
            r.x = fmaxf(acc1[u].x, 0.f);
            r.y = fmaxf(acc1[u].y, 0.f);
            r.z = fmaxf(acc1[u].z, 0.f);
            r.w = fmaxf(acc1[u].w, 0.f);
            *(float4*)&s_lds[(tbase + u) * H2 + j0] = r;
        }
    }
    __syncthreads();

    // ---- GEMM2 + residual ----
    {
        const int i0 = (tid & 31) << 2;    // 0..124
        const int g = tid >> 5;            // 0..7 -> nodes g, g+8
        float4 acc2[2];
        const float4 bv = *(const float4*)(b2 + i0);
        acc2[0] = bv; acc2[1] = bv;
        for (int k = 0; k < H2; k += 4) {
            float4 w[4];
            #pragma unroll
            for (int q = 0; q < 4; ++q)
                w[q] = *(const float4*)(W2 + (size_t)(k + q) * D + i0);
            #pragma unroll
            for (int u = 0; u < 2; ++u) {
                const float4 a = *(const float4*)&s_lds[(g + u * 8) * H2 + k];
                acc2[u].x = fmaf(a.x, w[0].x, acc2[u].x);
                acc2[u].y = fmaf(a.x, w[0].y, acc2[u].y);
                acc2[u].z = fmaf(a.x, w[0].z, acc2[u].z);
                acc2[u].w = fmaf(a.x, w[0].w, acc2[u].w);
                acc2[u].x = fmaf(a.y, w[1].x, acc2[u].x);
                acc2[u].y = fmaf(a.y, w[1].y, acc2[u].y);
                acc2[u].z = fmaf(a.y, w[1].z, acc2[u].z);
                acc2[u].w = fmaf(a.y, w[1].w, acc2[u].w);
                acc2[u].x = fmaf(a.z, w[2].x, acc2[u].x);
                acc2[u].y = fmaf(a.z, w[2].y, acc2[u].y);
                acc2[u].z = fmaf(a.z, w[2].z, acc2[u].z);
                acc2[u].w = fmaf(a.z, w[2].w, acc2[u].w);
                acc2[u].x = fmaf(a.w, w[3].x, acc2[u].x);
                acc2[u].y = fmaf(a.w, w[3].y, acc2[u].y);
                acc2[u].z = fmaf(a.w, w[3].z, acc2[u].z);
                acc2[u].w = fmaf(a.w, w[3].w, acc2[u].w);
            }
        }
        const float ep = 1.0f + eps[0];
        #pragma unroll
        for (int u = 0; u < 2; ++u) {
            const int node = node0 + g + u * 8;
            const f4 hv = ldg(h + (size_t)node * D + i0);
            f4 o;
            o[0] = fmaf(ep, hv[0], acc2[u].x);
            o[1] = fmaf(ep, hv[1], acc2[u].y);
            o[2] = fmaf(ep, hv[2], acc2[u].z);
            o[3] = fmaf(ep, hv[3], acc2[u].w);
            __builtin_nontemporal_store(o, (f4*)(out + (size_t)node * D + i0));
        }
    }
}

extern "C" void kernel_launch(void* const* d_in, const int* in_sizes, int n_in,
                              void* d_out, int out_size, void* d_ws, size_t ws_size,
                              hipStream_t stream) {
    const float* h   = (const float*)d_in[0];
    const float* ea  = (const float*)d_in[1];
    const int*   src = (const int*)d_in[2];
    const int*   dst = (const int*)d_in[3];
    const float* W1  = (const float*)d_in[4];
    const float* b1  = (const float*)d_in[5];
    const float* W2  = (const float*)d_in[6];
    const float* b2  = (const float*)d_in[7];
    const float* eps = (const float*)d_in[8];
    float* out = (float*)d_out;

    char* ws = (char*)d_ws;
    int*  counts    = (int*)ws;                    // 200 KB
    int*  scanned   = (int*)(ws + 256 * 1024);     // 200 KB
    int*  offsets   = (int*)(ws + 512 * 1024);     // 200 KB (+1)
    int*  cursor    = (int*)(ws + 768 * 1024);     // 200 KB
    int*  blocksums = (int*)(ws + 1008 * 1024);    // 1 KB
    int*  blockbase = (int*)(ws + 1012 * 1024);    // 1 KB
    int2* perm2     = (int2*)(ws + 1024 * 1024);   // 4.8 MB

    hipMemsetAsync(counts, 0, N_NODES * sizeof(int), stream);

    const int eblocks = (N_EDGES + 255) / 256;     // 2344
    const int nblocks = (N_NODES + 255) / 256;     // 196

    hist_kernel<<<eblocks, 256, 0, stream>>>(dst, counts);
    scan1_kernel<<<nblocks, 256, 0, stream>>>(counts, scanned, blocksums);
    scan2_kernel<<<1, 256, 0, stream>>>(blocksums, blockbase, nblocks);
    scan3_kernel<<<nblocks, 256, 0, stream>>>(scanned, blockbase, offsets, cursor);
    scatter_kernel<<<eblocks, 256, 0, stream>>>(src, dst, cursor, perm2);
    fused_kernel<<<N_NODES / TN, 256, 0, stream>>>(
        h, ea, offsets, perm2, W1, b1, W2, b2, eps, out);
}

// Round 5
// 595.341 us; speedup vs baseline: 1.4531x; 1.1025x over previous
//
#include <hip/hip_runtime.h>

#define N_NODES 50000
#define N_EDGES 600000
#define D 128
#define H2 256
#define TN 16      // nodes per fused block (50000/16 = 3125 exactly)
#define MAXC 2048  // perm chunk capacity in LDS (16KB region = 2048 int2)

// LDS float offsets (total 8192 floats = 32 KB)
#define AOFF 0      // aggr  [16][128]  (8 KB)   [0, 2048)
#define WOFF 2048   // wtile 2048 floats (8 KB)  [2048, 4096)
#define HOFF 4096   // hidden[16][256] (16 KB)   [4096, 8192); s_perm aliases this

typedef float f4 __attribute__((ext_vector_type(4)));

__device__ __forceinline__ f4 ldg_nt(const float* p) {
    return __builtin_nontemporal_load((const f4*)p);
}
__device__ __forceinline__ f4 ldg(const float* p) {
    return *(const f4*)p;
}

// ---------------------------------------------------------------------------
// Stage 1: histogram of dst -> counts[50000]
__global__ __launch_bounds__(256) void hist_kernel(const int* __restrict__ dst,
                                                   int* __restrict__ counts) {
    unsigned int e = blockIdx.x * 256u + threadIdx.x;
    if (e < N_EDGES) atomicAdd(&counts[dst[e]], 1);
}

// Stage 2a: block-local exclusive scan (196 blocks x 256 threads)
__global__ __launch_bounds__(256) void scan1_kernel(const int* __restrict__ counts,
                                                    int* __restrict__ scanned,
                                                    int* __restrict__ blocksums) {
    __shared__ int wsum[4];
    const int tid = threadIdx.x;
    const int lane = tid & 63;
    const int wv = tid >> 6;
    const int i = blockIdx.x * 256 + tid;
    const int cval = (i < N_NODES) ? counts[i] : 0;
    int x = cval;
    #pragma unroll
    for (int d = 1; d < 64; d <<= 1) {
        int t = __shfl_up(x, d, 64);
        if (lane >= d) x += t;
    }
    if (lane == 63) wsum[wv] = x;
    __syncthreads();
    if (tid == 0) {
        int s = 0;
        #pragma unroll
        for (int w = 0; w < 4; ++w) { s += wsum[w]; wsum[w] = s; }
    }
    __syncthreads();
    const int prefix = (wv > 0 ? wsum[wv - 1] : 0) + (x - cval);
    if (i < N_NODES) scanned[i] = prefix;
    if (tid == 0) blocksums[blockIdx.x] = wsum[3];
}

// Stage 2b: exclusive scan of the 196 block sums (1 block, 256 threads)
__global__ __launch_bounds__(256) void scan2_kernel(const int* __restrict__ blocksums,
                                                    int* __restrict__ blockbase, int nb) {
    __shared__ int wsum[4];
    const int tid = threadIdx.x;
    const int lane = tid & 63;
    const int wv = tid >> 6;
    const int cval = (tid < nb) ? blocksums[tid] : 0;
    int x = cval;
    #pragma unroll
    for (int d = 1; d < 64; d <<= 1) {
        int t = __shfl_up(x, d, 64);
        if (lane >= d) x += t;
    }
    if (lane == 63) wsum[wv] = x;
    __syncthreads();
    if (tid == 0) {
        int s = 0;
        #pragma unroll
        for (int w = 0; w < 4; ++w) { s += wsum[w]; wsum[w] = s; }
    }
    __syncthreads();
    if (tid < nb) blockbase[tid] = (wv > 0 ? wsum[wv - 1] : 0) + (x - cval);
}

// Stage 2c: add block bases -> offsets, prime cursor
__global__ __launch_bounds__(256) void scan3_kernel(const int* __restrict__ scanned,
                                                    const int* __restrict__ blockbase,
                                                    int* __restrict__ offsets,
                                                    int* __restrict__ cursor) {
    const int i = blockIdx.x * 256 + threadIdx.x;
    if (i < N_NODES) {
        const int v = scanned[i] + blockbase[blockIdx.x];
        offsets[i] = v;
        cursor[i] = v;
    }
    if (i == 0) offsets[N_NODES] = N_EDGES;
}

// Stage 3: scatter edges into dst-sorted order. perm2[p] = (edge_id, src).
__global__ __launch_bounds__(256) void scatter_kernel(const int* __restrict__ src,
                                                      const int* __restrict__ dst,
                                                      int* __restrict__ cursor,
                                                      int2* __restrict__ perm2) {
    unsigned int e = blockIdx.x * 256u + threadIdx.x;
    if (e >= N_EDGES) return;
    const int d = dst[e];
    const int p = atomicAdd(&cursor[d], 1);
    perm2[p] = make_int2((int)e, src[e]);
}

// ---------------------------------------------------------------------------
// Stage 4: fused gather + MLP + residual. Block = 16 nodes, 256 threads.
// Gather: 16-lane subgroup per node, 4-edge unroll, NT ea loads.
// GEMMs: W1/W2 staged in LDS k-tiles (kills the 4-8x redundant per-row-group
// W reloads that were eating L1 BW + VMEM issue slots).
// LDS 32 KB: aggr[0,8K) | wtile[8K,16K) | hidden[16K,32K)=s_perm alias.
// 5 blocks x 32 KB = 160 KB/CU exactly.
__global__ __launch_bounds__(256, 5) void fused_kernel(
    const float* __restrict__ h, const float* __restrict__ ea,
    const int* __restrict__ offsets, const int2* __restrict__ perm2,
    const float* __restrict__ W1, const float* __restrict__ b1,
    const float* __restrict__ W2, const float* __restrict__ b2,
    const float* __restrict__ eps, float* __restrict__ out)
{
    __shared__ float s_lds[8192];   // 32 KB
    int2* s_perm = (int2*)&s_lds[HOFF];

    const int tid = threadIdx.x;
    const int t  = tid >> 4;            // node 0..15
    const int c8 = (tid & 15) << 3;     // float col 0..120 (8 per lane)
    const int node0 = blockIdx.x * TN;
    const int blkbeg = offsets[node0];
    const int blkend = offsets[node0 + TN];
    const int nbeg = offsets[node0 + t];
    const int nend = offsets[node0 + t + 1];

    f4 a0 = (f4)(0.f);
    f4 a1 = (f4)(0.f);

    for (int cb = blkbeg; cb < blkend; cb += MAXC) {
        const int cnt = min(blkend - cb, MAXC);
        __syncthreads();   // prior chunk's s_perm reads done
        for (int i = tid; i < cnt; i += 256) s_perm[i] = perm2[cb + i];
        __syncthreads();
        const int lo = max(nbeg - cb, 0);
        const int hi = min(nend - cb, cnt);
        int j = lo;
        // main: 4 edges per iteration, loads hoisted
        for (; j + 3 < hi; j += 4) {
            int2 p[4];
            #pragma unroll
            for (int q = 0; q < 4; ++q) p[q] = s_perm[j + q];
            f4 ev0[4], ev1[4], hv0[4], hv1[4];
            #pragma unroll
            for (int q = 0; q < 4; ++q) {
                const float* er = ea + (size_t)p[q].x * D + c8;
                const float* hr = h  + (size_t)p[q].y * D + c8;
                ev0[q] = ldg_nt(er);
                ev1[q] = ldg_nt(er + 4);
                hv0[q] = ldg(hr);
                hv1[q] = ldg(hr + 4);
            }
            #pragma unroll
            for (int q = 0; q < 4; ++q) {
                a0 += ev0[q] + hv0[q];
                a1 += ev1[q] + hv1[q];
            }
        }
        // tail: 0..3 edges
        for (; j < hi; ++j) {
            const int2 p = s_perm[j];
            const float* er = ea + (size_t)p.x * D + c8;
            const float* hr = h  + (size_t)p.y * D + c8;
            a0 += ldg_nt(er)     + ldg(hr);
            a1 += ldg_nt(er + 4) + ldg(hr + 4);
        }
    }
    __syncthreads();   // all s_perm reads done
    *(f4*)&s_lds[AOFF + t * D + c8]     = a0;
    *(f4*)&s_lds[AOFF + t * D + c8 + 4] = a1;
    // (visibility of aggr ensured by the barrier at top of GEMM1's k-loop)

    // ---- GEMM1: hidden = relu(aggr @ W1 + b1), W1 staged in 8-row k-tiles --
    const int j0 = (tid & 63) << 2;    // 0..252
    const int tbase = (tid >> 6) << 2; // 0,4,8,12
    {
        float4 acc1[4];
        const float4 bv = *(const float4*)(b1 + j0);
        #pragma unroll
        for (int q = 0; q < 4; ++q) acc1[q] = bv;
        for (int k0 = 0; k0 < D; k0 += 8) {
            __syncthreads();  // aggr visible (first iter) / prior wtile reads done
            // stage W1[k0..k0+8][0..256] = 512 f4; 2 f4 per thread
            {
                const float4* srcw = (const float4*)(W1 + (size_t)k0 * H2);
                float4* dstl = (float4*)&s_lds[WOFF];
                dstl[tid]       = srcw[tid];
                dstl[tid + 256] = srcw[tid + 256];
            }
            __syncthreads();
            #pragma unroll
            for (int kk = 0; kk < 8; kk += 4) {
                float4 w[4];
                #pragma unroll
                for (int q = 0; q < 4; ++q)
                    w[q] = *(const float4*)&s_lds[WOFF + (kk + q) * H2 + j0];
                #pragma unroll
                for (int u = 0; u < 4; ++u) {
                    const float4 a = *(const float4*)&s_lds[AOFF + (tbase + u) * D + k0 + kk];
                    acc1[u].x = fmaf(a.x, w[0].x, acc1[u].x);
                    acc1[u].y = fmaf(a.x, w[0].y, acc1[u].y);
                    acc1[u].z = fmaf(a.x, w[0].z, acc1[u].z);
                    acc1[u].w = fmaf(a.x, w[0].w, acc1[u].w);
                    acc1[u].x = fmaf(a.y, w[1].x, acc1[u].x);
                    acc1[u].y = fmaf(a.y, w[1].y, acc1[u].y);
                    acc1[u].z = fmaf(a.y, w[1].z, acc1[u].z);
                    acc1[u].w = fmaf(a.y, w[1].w, acc1[u].w);
                    acc1[u].x = fmaf(a.z, w[2].x, acc1[u].x);
                    acc1[u].y = fmaf(a.z, w[2].y, acc1[u].y);
                    acc1[u].z = fmaf(a.z, w[2].z, acc1[u].z);
                    acc1[u].w = fmaf(a.z, w[2].w, acc1[u].w);
                    acc1[u].x = fmaf(a.w, w[3].x, acc1[u].x);
                    acc1[u].y = fmaf(a.w, w[3].y, acc1[u].y);
                    acc1[u].z = fmaf(a.w, w[3].z, acc1[u].z);
                    acc1[u].w = fmaf(a.w, w[3].w, acc1[u].w);
                }
            }
        }
        // write hidden (disjoint from aggr/wtile regions; s_perm dead)
        #pragma unroll
        for (int u = 0; u < 4; ++u) {
            float4 r;
            r.x = fmaxf(acc1[u].x, 0.f);
            r.y = fmaxf(acc1[u].y, 0.f);
            r.z = fmaxf(acc1[u].z, 0.f);
            r.w = fmaxf(acc1[u].w, 0.f);
            *(float4*)&s_lds[HOFF + (tbase + u) * H2 + j0] = r;
        }
    }

    // ---- GEMM2 + residual, W2 staged in 16-row k-tiles ----
    {
        const int i0 = (tid & 31) << 2;    // 0..124
        const int g = tid >> 5;            // 0..7 -> nodes g, g+8
        float4 acc2[2];
        const float4 bv = *(const float4*)(b2 + i0);
        acc2[0] = bv; acc2[1] = bv;
        for (int k0 = 0; k0 < H2; k0 += 16) {
            __syncthreads();  // hidden visible (first iter) / prior wtile reads done
            // stage W2[k0..k0+16][0..128] = 512 f4; 2 f4 per thread
            {
                const float4* srcw = (const float4*)(W2 + (size_t)k0 * D);
                float4* dstl = (float4*)&s_lds[WOFF];
                dstl[tid]       = srcw[tid];
                dstl[tid + 256] = srcw[tid + 256];
            }
            __syncthreads();
            #pragma unroll
            for (int kk = 0; kk < 16; kk += 4) {
                float4 w[4];
                #pragma unroll
                for (int q = 0; q < 4; ++q)
                    w[q] = *(const float4*)&s_lds[WOFF + (kk + q) * D + i0];
                #pragma unroll
                for (int u = 0; u < 2; ++u) {
                    const float4 a = *(const float4*)&s_lds[HOFF + (g + u * 8) * H2 + k0 + kk];
                    acc2[u].x = fmaf(a.x, w[0].x, acc2[u].x);
                    acc2[u].y = fmaf(a.x, w[0].y, acc2[u].y);
                    acc2[u].z = fmaf(a.x, w[0].z, acc2[u].z);
                    acc2[u].w = fmaf(a.x, w[0].w, acc2[u].w);
                    acc2[u].x = fmaf(a.y, w[1].x, acc2[u].x);
                    acc2[u].y = fmaf(a.y, w[1].y, acc2[u].y);
                    acc2[u].z = fmaf(a.y, w[1].z, acc2[u].z);
                    acc2[u].w = fmaf(a.y, w[1].w, acc2[u].w);
                    acc2[u].x = fmaf(a.z, w[2].x, acc2[u].x);
                    acc2[u].y = fmaf(a.z, w[2].y, acc2[u].y);
                    acc2[u].z = fmaf(a.z, w[2].z, acc2[u].z);
                    acc2[u].w = fmaf(a.z, w[2].w, acc2[u].w);
                    acc2[u].x = fmaf(a.w, w[3].x, acc2[u].x);
                    acc2[u].y = fmaf(a.w, w[3].y, acc2[u].y);
                    acc2[u].z = fmaf(a.w, w[3].z, acc2[u].z);
                    acc2[u].w = fmaf(a.w, w[3].w, acc2[u].w);
                }
            }
        }
        const float ep = 1.0f + eps[0];
        #pragma unroll
        for (int u = 0; u < 2; ++u) {
            const int node = node0 + g + u * 8;
            const f4 hv = ldg(h + (size_t)node * D + i0);
            f4 o;
            o[0] = fmaf(ep, hv[0], acc2[u].x);
            o[1] = fmaf(ep, hv[1], acc2[u].y);
            o[2] = fmaf(ep, hv[2], acc2[u].z);
            o[3] = fmaf(ep, hv[3], acc2[u].w);
            __builtin_nontemporal_store(o, (f4*)(out + (size_t)node * D + i0));
        }
    }
}

extern "C" void kernel_launch(void* const* d_in, const int* in_sizes, int n_in,
                              void* d_out, int out_size, void* d_ws, size_t ws_size,
                              hipStream_t stream) {
    const float* h   = (const float*)d_in[0];
    const float* ea  = (const float*)d_in[1];
    const int*   src = (const int*)d_in[2];
    const int*   dst = (const int*)d_in[3];
    const float* W1  = (const float*)d_in[4];
    const float* b1  = (const float*)d_in[5];
    const float* W2  = (const float*)d_in[6];
    const float* b2  = (const float*)d_in[7];
    const float* eps = (const float*)d_in[8];
    float* out = (float*)d_out;

    char* ws = (char*)d_ws;
    int*  counts    = (int*)ws;                    // 200 KB
    int*  scanned   = (int*)(ws + 256 * 1024);     // 200 KB
    int*  offsets   = (int*)(ws + 512 * 1024);     // 200 KB (+1)
    int*  cursor    = (int*)(ws + 768 * 1024);     // 200 KB
    int*  blocksums = (int*)(ws + 1008 * 1024);    // 1 KB
    int*  blockbase = (int*)(ws + 1012 * 1024);    // 1 KB
    int2* perm2     = (int2*)(ws + 1024 * 1024);   // 4.8 MB

    hipMemsetAsync(counts, 0, N_NODES * sizeof(int), stream);

    const int eblocks = (N_EDGES + 255) / 256;     // 2344
    const int nblocks = (N_NODES + 255) / 256;     // 196

    hist_kernel<<<eblocks, 256, 0, stream>>>(dst, counts);
    scan1_kernel<<<nblocks, 256, 0, stream>>>(counts, scanned, blocksums);
    scan2_kernel<<<1, 256, 0, stream>>>(blocksums, blockbase, nblocks);
    scan3_kernel<<<nblocks, 256, 0, stream>>>(scanned, blockbase, offsets, cursor);
    scatter_kernel<<<eblocks, 256, 0, stream>>>(src, dst, cursor, perm2);
    fused_kernel<<<N_NODES / TN, 256, 0, stream>>>(
        h, ea, offsets, perm2, W1, b1, W2, b2, eps, out);
}

// Round 7
// 594.564 us; speedup vs baseline: 1.4550x; 1.0013x over previous
//
#include <hip/hip_runtime.h>

#define N_NODES 50000
#define N_EDGES 600000
#define D 128
#define H2 256
#define TN 16      // nodes per fused block (50000/16 = 3125 exactly)
#define MAXC 2048  // perm chunk capacity in LDS (16KB <= 20KB region)

typedef float f4 __attribute__((ext_vector_type(4)));

__device__ __forceinline__ f4 ldg_nt(const float* p) {
    return __builtin_nontemporal_load((const f4*)p);
}
__device__ __forceinline__ f4 ldg(const float* p) {
    return *(const f4*)p;
}

// pack two f32 -> one u32 of 2x bf16 (round-to-nearest-even)
__device__ __forceinline__ unsigned int bfpair(float lo, float hi) {
    unsigned int ul = __float_as_uint(lo), uh = __float_as_uint(hi);
    ul += 0x7FFFu + ((ul >> 16) & 1u);
    uh += 0x7FFFu + ((uh >> 16) & 1u);
    return (ul >> 16) | (uh & 0xFFFF0000u);
}
__device__ __forceinline__ float bflo(unsigned int u) { return __uint_as_float(u << 16); }
__device__ __forceinline__ float bfhi(unsigned int u) { return __uint_as_float(u & 0xFFFF0000u); }

// ---------------------------------------------------------------------------
// Stage 1: histogram of dst -> counts[50000]
__global__ __launch_bounds__(256) void hist_kernel(const int* __restrict__ dst,
                                                   int* __restrict__ counts) {
    unsigned int e = blockIdx.x * 256u + threadIdx.x;
    if (e < N_EDGES) atomicAdd(&counts[dst[e]], 1);
}

// Stage 2a: block-local exclusive scan (196 blocks x 256 threads)
__global__ __launch_bounds__(256) void scan1_kernel(const int* __restrict__ counts,
                                                    int* __restrict__ scanned,
                                                    int* __restrict__ blocksums) {
    __shared__ int wsum[4];
    const int tid = threadIdx.x;
    const int lane = tid & 63;
    const int wv = tid >> 6;
    const int i = blockIdx.x * 256 + tid;
    const int cval = (i < N_NODES) ? counts[i] : 0;
    int x = cval;
    #pragma unroll
    for (int d = 1; d < 64; d <<= 1) {
        int t = __shfl_up(x, d, 64);
        if (lane >= d) x += t;
    }
    if (lane == 63) wsum[wv] = x;
    __syncthreads();
    if (tid == 0) {
        int s = 0;
        #pragma unroll
        for (int w = 0; w < 4; ++w) { s += wsum[w]; wsum[w] = s; }
    }
    __syncthreads();
    const int prefix = (wv > 0 ? wsum[wv - 1] : 0) + (x - cval);
    if (i < N_NODES) scanned[i] = prefix;
    if (tid == 0) blocksums[blockIdx.x] = wsum[3];
}

// Stage 2b: exclusive scan of the 196 block sums (1 block, 256 threads)
__global__ __launch_bounds__(256) void scan2_kernel(const int* __restrict__ blocksums,
                                                    int* __restrict__ blockbase, int nb) {
    __shared__ int wsum[4];
    const int tid = threadIdx.x;
    const int lane = tid & 63;
    const int wv = tid >> 6;
    const int cval = (tid < nb) ? blocksums[tid] : 0;
    int x = cval;
    #pragma unroll
    for (int d = 1; d < 64; d <<= 1) {
        int t = __shfl_up(x, d, 64);
        if (lane >= d) x += t;
    }
    if (lane == 63) wsum[wv] = x;
    __syncthreads();
    if (tid == 0) {
        int s = 0;
        #pragma unroll
        for (int w = 0; w < 4; ++w) { s += wsum[w]; wsum[w] = s; }
    }
    __syncthreads();
    if (tid < nb) blockbase[tid] = (wv > 0 ? wsum[wv - 1] : 0) + (x - cval);
}

// Stage 2c: add block bases -> offsets, prime cursor
__global__ __launch_bounds__(256) void scan3_kernel(const int* __restrict__ scanned,
                                                    const int* __restrict__ blockbase,
                                                    int* __restrict__ offsets,
                                                    int* __restrict__ cursor) {
    const int i = blockIdx.x * 256 + threadIdx.x;
    if (i < N_NODES) {
        const int v = scanned[i] + blockbase[blockIdx.x];
        offsets[i] = v;
        cursor[i] = v;
    }
    if (i == 0) offsets[N_NODES] = N_EDGES;
}

// Stage 3: scatter edges into dst-sorted order. perm2[p] = (edge_id, src).
__global__ __launch_bounds__(256) void scatter_kernel(const int* __restrict__ src,
                                                      const int* __restrict__ dst,
                                                      int* __restrict__ cursor,
                                                      int2* __restrict__ perm2) {
    unsigned int e = blockIdx.x * 256u + threadIdx.x;
    if (e >= N_EDGES) return;
    const int d = dst[e];
    const int p = atomicAdd(&cursor[d], 1);
    perm2[p] = make_int2((int)e, src[e]);
}

// ---------------------------------------------------------------------------
// Stage 4: fused gather + MLP + residual. Block = 16 nodes, 256 threads.
// LDS 20 KB total -> 8 blocks/CU (160 KB):
//   gather phase : s_perm (2048 int2, 16 KB) aliases everything
//   GEMM phase   : aggr bf16 [0,4K)B | wtile f32 [4K,12K)B | hidden bf16 [12K,20K)B
// aggr/hidden stored as RNE-rounded bf16 (threshold has bf16-scale headroom);
// W tiles stay fp32. Unpack = 1 shift/mask per element.
__global__ __launch_bounds__(256, 8) void fused_kernel(
    const float* __restrict__ h, const float* __restrict__ ea,
    const int* __restrict__ offsets, const int2* __restrict__ perm2,
    const float* __restrict__ W1, const float* __restrict__ b1,
    const float* __restrict__ W2, const float* __restrict__ b2,
    const float* __restrict__ eps, float* __restrict__ out)
{
    __shared__ float s_lds[5120];   // 20 KB
    int2* s_perm = (int2*)s_lds;
    unsigned int* s_aggr = (unsigned int*)s_lds;            // [16][64] u32 (bf16 pairs)
    float* s_w = s_lds + 1024;                              // 2048 f32 (8 KB)
    unsigned int* s_hid = (unsigned int*)(s_lds + 3072);    // [16][128] u32 (bf16 pairs)

    const int tid = threadIdx.x;
    const int t  = tid >> 4;            // node 0..15
    const int c8 = (tid & 15) << 3;     // float col 0..120 (8 per lane)
    const int node0 = blockIdx.x * TN;
    const int blkbeg = offsets[node0];
    const int blkend = offsets[node0 + TN];
    const int nbeg = offsets[node0 + t];
    const int nend = offsets[node0 + t + 1];

    f4 a0 = (f4)(0.f);
    f4 a1 = (f4)(0.f);

    for (int cb = blkbeg; cb < blkend; cb += MAXC) {
        const int cnt = min(blkend - cb, MAXC);
        __syncthreads();   // prior chunk's s_perm reads done
        for (int i = tid; i < cnt; i += 256) s_perm[i] = perm2[cb + i];
        __syncthreads();
        const int lo = max(nbeg - cb, 0);
        const int hi = min(nend - cb, cnt);
        int j = lo;
        // main: 4 edges per iteration, loads hoisted
        for (; j + 3 < hi; j += 4) {
            int2 p[4];
            #pragma unroll
            for (int q = 0; q < 4; ++q) p[q] = s_perm[j + q];
            f4 ev0[4], ev1[4], hv0[4], hv1[4];
            #pragma unroll
            for (int q = 0; q < 4; ++q) {
                const float* er = ea + (size_t)p[q].x * D + c8;
                const float* hr = h  + (size_t)p[q].y * D + c8;
                ev0[q] = ldg_nt(er);
                ev1[q] = ldg_nt(er + 4);
                hv0[q] = ldg(hr);
                hv1[q] = ldg(hr + 4);
            }
            #pragma unroll
            for (int q = 0; q < 4; ++q) {
                a0 += ev0[q] + hv0[q];
                a1 += ev1[q] + hv1[q];
            }
        }
        // tail: 0..3 edges
        for (; j < hi; ++j) {
            const int2 p = s_perm[j];
            const float* er = ea + (size_t)p.x * D + c8;
            const float* hr = h  + (size_t)p.y * D + c8;
            a0 += ldg_nt(er)     + ldg(hr);
            a1 += ldg_nt(er + 4) + ldg(hr + 4);
        }
    }
    __syncthreads();   // all s_perm reads done; LDS free for GEMM-phase layout
    {
        unsigned int* ad = s_aggr + t * 64 + (c8 >> 1);
        ad[0] = bfpair(a0[0], a0[1]);
        ad[1] = bfpair(a0[2], a0[3]);
        ad[2] = bfpair(a1[0], a1[1]);
        ad[3] = bfpair(a1[2], a1[3]);
    }
    // (aggr visibility ensured by the barrier at top of GEMM1's k-loop)

    // ---- GEMM1: hidden = relu(aggr @ W1 + b1), W1 staged in 8-row k-tiles --
    const int j0 = (tid & 63) << 2;    // 0..252
    const int tbase = (tid >> 6) << 2; // 0,4,8,12
    {
        float4 acc1[4];
        const float4 bv = *(const float4*)(b1 + j0);
        #pragma unroll
        for (int q = 0; q < 4; ++q) acc1[q] = bv;
        for (int k0 = 0; k0 < D; k0 += 8) {
            __syncthreads();  // aggr visible (first iter) / prior wtile reads done
            // stage W1[k0..k0+8][0..256] = 512 f4; 2 f4 per thread
            {
                const float4* srcw = (const float4*)(W1 + (size_t)k0 * H2);
                float4* dstl = (float4*)s_w;
                dstl[tid]       = srcw[tid];
                dstl[tid + 256] = srcw[tid + 256];
            }
            __syncthreads();
            #pragma unroll
            for (int kk = 0; kk < 8; kk += 4) {
                float4 w[4];
                #pragma unroll
                for (int q = 0; q < 4; ++q)
                    w[q] = *(const float4*)&s_w[(kk + q) * H2 + j0];
                #pragma unroll
                for (int u = 0; u < 4; ++u) {
                    const unsigned int* ar = s_aggr + (tbase + u) * 64 + ((k0 + kk) >> 1);
                    const unsigned int u01 = ar[0];
                    const unsigned int u23 = ar[1];
                    float4 a;
                    a.x = bflo(u01); a.y = bfhi(u01);
                    a.z = bflo(u23); a.w = bfhi(u23);
                    acc1[u].x = fmaf(a.x, w[0].x, acc1[u].x);
                    acc1[u].y = fmaf(a.x, w[0].y, acc1[u].y);
                    acc1[u].z = fmaf(a.x, w[0].z, acc1[u].z);
                    acc1[u].w = fmaf(a.x, w[0].w, acc1[u].w);
                    acc1[u].x = fmaf(a.y, w[1].x, acc1[u].x);
                    acc1[u].y = fmaf(a.y, w[1].y, acc1[u].y);
                    acc1[u].z = fmaf(a.y, w[1].z, acc1[u].z);
                    acc1[u].w = fmaf(a.y, w[1].w, acc1[u].w);
                    acc1[u].x = fmaf(a.z, w[2].x, acc1[u].x);
                    acc1[u].y = fmaf(a.z, w[2].y, acc1[u].y);
                    acc1[u].z = fmaf(a.z, w[2].z, acc1[u].z);
                    acc1[u].w = fmaf(a.z, w[2].w, acc1[u].w);
                    acc1[u].x = fmaf(a.w, w[3].x, acc1[u].x);
                    acc1[u].y = fmaf(a.w, w[3].y, acc1[u].y);
                    acc1[u].z = fmaf(a.w, w[3].z, acc1[u].z);
                    acc1[u].w = fmaf(a.w, w[3].w, acc1[u].w);
                }
            }
        }
        // write hidden as bf16 (region disjoint from aggr/wtile)
        #pragma unroll
        for (int u = 0; u < 4; ++u) {
            unsigned int* hd = s_hid + (tbase + u) * 128 + (j0 >> 1);
            hd[0] = bfpair(fmaxf(acc1[u].x, 0.f), fmaxf(acc1[u].y, 0.f));
            hd[1] = bfpair(fmaxf(acc1[u].z, 0.f), fmaxf(acc1[u].w, 0.f));
        }
    }

    // ---- GEMM2 + residual, W2 staged in 16-row k-tiles ----
    {
        const int i0 = (tid & 31) << 2;    // 0..124
        const int g = tid >> 5;            // 0..7 -> nodes g, g+8
        float4 acc2[2];
        const float4 bv = *(const float4*)(b2 + i0);
        acc2[0] = bv; acc2[1] = bv;
        for (int k0 = 0; k0 < H2; k0 += 16) {
            __syncthreads();  // hidden visible (first iter) / prior wtile reads done
            // stage W2[k0..k0+16][0..128] = 512 f4; 2 f4 per thread
            {
                const float4* srcw = (const float4*)(W2 + (size_t)k0 * D);
                float4* dstl = (float4*)s_w;
                dstl[tid]       = srcw[tid];
                dstl[tid + 256] = srcw[tid + 256];
            }
            __syncthreads();
            #pragma unroll
            for (int kk = 0; kk < 16; kk += 4) {
                float4 w[4];
                #pragma unroll
                for (int q = 0; q < 4; ++q)
                    w[q] = *(const float4*)&s_w[(kk + q) * D + i0];
                #pragma unroll
                for (int u = 0; u < 2; ++u) {
                    const unsigned int* hr = s_hid + (g + u * 8) * 128 + ((k0 + kk) >> 1);
                    const unsigned int u01 = hr[0];
                    const unsigned int u23 = hr[1];
                    float4 a;
                    a.x = bflo(u01); a.y = bfhi(u01);
                    a.z = bflo(u23); a.w = bfhi(u23);
                    acc2[u].x = fmaf(a.x, w[0].x, acc2[u].x);
                    acc2[u].y = fmaf(a.x, w[0].y, acc2[u].y);
                    acc2[u].z = fmaf(a.x, w[0].z, acc2[u].z);
                    acc2[u].w = fmaf(a.x, w[0].w, acc2[u].w);
                    acc2[u].x = fmaf(a.y, w[1].x, acc2[u].x);
                    acc2[u].y = fmaf(a.y, w[1].y, acc2[u].y);
                    acc2[u].z = fmaf(a.y, w[1].z, acc2[u].z);
                    acc2[u].w = fmaf(a.y, w[1].w, acc2[u].w);
                    acc2[u].x = fmaf(a.z, w[2].x, acc2[u].x);
                    acc2[u].y = fmaf(a.z, w[2].y, acc2[u].y);
                    acc2[u].z = fmaf(a.z, w[2].z, acc2[u].z);
                    acc2[u].w = fmaf(a.z, w[2].w, acc2[u].w);
                    acc2[u].x = fmaf(a.w, w[3].x, acc2[u].x);
                    acc2[u].y = fmaf(a.w, w[3].y, acc2[u].y);
                    acc2[u].z = fmaf(a.w, w[3].z, acc2[u].z);
                    acc2[u].w = fmaf(a.w, w[3].w, acc2[u].w);
                }
            }
        }
        const float ep = 1.0f + eps[0];
        #pragma unroll
        for (int u = 0; u < 2; ++u) {
            const int node = node0 + g + u * 8;
            const f4 hv = ldg(h + (size_t)node * D + i0);
            f4 o;
            o[0] = fmaf(ep, hv[0], acc2[u].x);
            o[1] = fmaf(ep, hv[1], acc2[u].y);
            o[2] = fmaf(ep, hv[2], acc2[u].z);
            o[3] = fmaf(ep, hv[3], acc2[u].w);
            __builtin_nontemporal_store(o, (f4*)(out + (size_t)node * D + i0));
        }
    }
}

extern "C" void kernel_launch(void* const* d_in, const int* in_sizes, int n_in,
                              void* d_out, int out_size, void* d_ws, size_t ws_size,
                              hipStream_t stream) {
    const float* h   = (const float*)d_in[0];
    const float* ea  = (const float*)d_in[1];
    const int*   src = (const int*)d_in[2];
    const int*   dst = (const int*)d_in[3];
    const float* W1  = (const float*)d_in[4];
    const float* b1  = (const float*)d_in[5];
    const float* W2  = (const float*)d_in[6];
    const float* b2  = (const float*)d_in[7];
    const float* eps = (const float*)d_in[8];
    float* out = (float*)d_out;

    char* ws = (char*)d_ws;
    int*  counts    = (int*)ws;                    // 200 KB
    int*  scanned   = (int*)(ws + 256 * 1024);     // 200 KB
    int*  offsets   = (int*)(ws + 512 * 1024);     // 200 KB (+1)
    int*  cursor    = (int*)(ws + 768 * 1024);     // 200 KB
    int*  blocksums = (int*)(ws + 1008 * 1024);    // 1 KB
    int*  blockbase = (int*)(ws + 1012 * 1024);    // 1 KB
    int2* perm2     = (int2*)(ws + 1024 * 1024);   // 4.8 MB

    hipMemsetAsync(counts, 0, N_NODES * sizeof(int), stream);

    const int eblocks = (N_EDGES + 255) / 256;     // 2344
    const int nblocks = (N_NODES + 255) / 256;     // 196

    hist_kernel<<<eblocks, 256, 0, stream>>>(dst, counts);
    scan1_kernel<<<nblocks, 256, 0, stream>>>(counts, scanned, blocksums);
    scan2_kernel<<<1, 256, 0, stream>>>(blocksums, blockbase, nblocks);
    scan3_kernel<<<nblocks, 256, 0, stream>>>(scanned, blockbase, offsets, cursor);
    scatter_kernel<<<eblocks, 256, 0, stream>>>(src, dst, cursor, perm2);
    fused_kernel<<<N_NODES / TN, 256, 0, stream>>>(
        h, ea, offsets, perm2, W1, b1, W2, b2, eps, out);
}

// Round 8
// 583.104 us; speedup vs baseline: 1.4836x; 1.0197x over previous
//
#include <hip/hip_runtime.h>

#define N_NODES 50000
#define N_EDGES 600000
#define D 128
#define H2 256
#define TN 16      // nodes per fused block (50000/16 = 3125 exactly)
#define MAXC 2048  // perm chunk capacity in LDS (16KB <= 20KB region)

typedef float f4 __attribute__((ext_vector_type(4)));
typedef unsigned int u4 __attribute__((ext_vector_type(4)));

__device__ __forceinline__ f4 ldg_nt(const float* p) {
    return __builtin_nontemporal_load((const f4*)p);
}
__device__ __forceinline__ f4 ldg(const float* p) {
    return *(const f4*)p;
}

// pack two f32 -> one u32 of 2x bf16 (round-to-nearest-even)
__device__ __forceinline__ unsigned int bfpair(float lo, float hi) {
    unsigned int ul = __float_as_uint(lo), uh = __float_as_uint(hi);
    ul += 0x7FFFu + ((ul >> 16) & 1u);
    uh += 0x7FFFu + ((uh >> 16) & 1u);
    return (ul >> 16) | (uh & 0xFFFF0000u);
}
__device__ __forceinline__ float bflo(unsigned int u) { return __uint_as_float(u << 16); }
__device__ __forceinline__ float bfhi(unsigned int u) { return __uint_as_float(u & 0xFFFF0000u); }

// ---------------------------------------------------------------------------
// Stage 0: h -> bf16 mirror (for the x12-reused gather operand only).
// 6.4M floats; thread handles 8 -> 800000 threads = 3125 blocks x 256.
__global__ __launch_bounds__(256) void hcvt_kernel(const float* __restrict__ h,
                                                   u4* __restrict__ hb4) {
    const int i = blockIdx.x * 256 + threadIdx.x;
    if (i < (N_NODES * D) / 8) {
        const f4 v0 = ldg(h + (size_t)i * 8);
        const f4 v1 = ldg(h + (size_t)i * 8 + 4);
        u4 o;
        o.x = bfpair(v0[0], v0[1]);
        o.y = bfpair(v0[2], v0[3]);
        o.z = bfpair(v1[0], v1[1]);
        o.w = bfpair(v1[2], v1[3]);
        hb4[i] = o;
    }
}

// ---------------------------------------------------------------------------
// Stage 1: histogram of dst -> counts[50000]
__global__ __launch_bounds__(256) void hist_kernel(const int* __restrict__ dst,
                                                   int* __restrict__ counts) {
    unsigned int e = blockIdx.x * 256u + threadIdx.x;
    if (e < N_EDGES) atomicAdd(&counts[dst[e]], 1);
}

// Stage 2a: block-local exclusive scan (196 blocks x 256 threads)
__global__ __launch_bounds__(256) void scan1_kernel(const int* __restrict__ counts,
                                                    int* __restrict__ scanned,
                                                    int* __restrict__ blocksums) {
    __shared__ int wsum[4];
    const int tid = threadIdx.x;
    const int lane = tid & 63;
    const int wv = tid >> 6;
    const int i = blockIdx.x * 256 + tid;
    const int cval = (i < N_NODES) ? counts[i] : 0;
    int x = cval;
    #pragma unroll
    for (int d = 1; d < 64; d <<= 1) {
        int t = __shfl_up(x, d, 64);
        if (lane >= d) x += t;
    }
    if (lane == 63) wsum[wv] = x;
    __syncthreads();
    if (tid == 0) {
        int s = 0;
        #pragma unroll
        for (int w = 0; w < 4; ++w) { s += wsum[w]; wsum[w] = s; }
    }
    __syncthreads();
    const int prefix = (wv > 0 ? wsum[wv - 1] : 0) + (x - cval);
    if (i < N_NODES) scanned[i] = prefix;
    if (tid == 0) blocksums[blockIdx.x] = wsum[3];
}

// Stage 2b: exclusive scan of the 196 block sums (1 block, 256 threads)
__global__ __launch_bounds__(256) void scan2_kernel(const int* __restrict__ blocksums,
                                                    int* __restrict__ blockbase, int nb) {
    __shared__ int wsum[4];
    const int tid = threadIdx.x;
    const int lane = tid & 63;
    const int wv = tid >> 6;
    const int cval = (tid < nb) ? blocksums[tid] : 0;
    int x = cval;
    #pragma unroll
    for (int d = 1; d < 64; d <<= 1) {
        int t = __shfl_up(x, d, 64);
        if (lane >= d) x += t;
    }
    if (lane == 63) wsum[wv] = x;
    __syncthreads();
    if (tid == 0) {
        int s = 0;
        #pragma unroll
        for (int w = 0; w < 4; ++w) { s += wsum[w]; wsum[w] = s; }
    }
    __syncthreads();
    if (tid < nb) blockbase[tid] = (wv > 0 ? wsum[wv - 1] : 0) + (x - cval);
}

// Stage 2c: add block bases -> offsets, prime cursor
__global__ __launch_bounds__(256) void scan3_kernel(const int* __restrict__ scanned,
                                                    const int* __restrict__ blockbase,
                                                    int* __restrict__ offsets,
                                                    int* __restrict__ cursor) {
    const int i = blockIdx.x * 256 + threadIdx.x;
    if (i < N_NODES) {
        const int v = scanned[i] + blockbase[blockIdx.x];
        offsets[i] = v;
        cursor[i] = v;
    }
    if (i == 0) offsets[N_NODES] = N_EDGES;
}

// Stage 3: scatter edges into dst-sorted order.
// perm2[p] = (e*D, src*D)  -- premultiplied element offsets (fit in int32).
__global__ __launch_bounds__(256) void scatter_kernel(const int* __restrict__ src,
                                                      const int* __restrict__ dst,
                                                      int* __restrict__ cursor,
                                                      int2* __restrict__ perm2) {
    unsigned int e = blockIdx.x * 256u + threadIdx.x;
    if (e >= N_EDGES) return;
    const int d = dst[e];
    const int p = atomicAdd(&cursor[d], 1);
    perm2[p] = make_int2((int)(e * D), src[e] * D);
}

// ---------------------------------------------------------------------------
// Stage 4: fused gather + MLP + residual. Block = 16 nodes, 256 threads.
// Gather: 16-lane subgroup per node; per edge 3 loads (ea f32x4 x2 NT, h
// bf16x8 x1); 4-edge unroll. h read from the bf16 mirror (halves h request
// bytes; 12.8 MB is far more cache-resident than 25.6). Residual uses fp32 h.
// LDS 20 KB -> up to 8 blocks/CU; launch_bounds(256,6) leaves VGPR room (~84)
// so the 4-edge load batch (~70 VGPRs) actually materializes.
//   gather phase : s_perm (2048 int2, 16 KB) aliases everything
//   GEMM phase   : aggr bf16 [0,4K)B | wtile f32 [4K,12K)B | hidden bf16 [12K,20K)B
__global__ __launch_bounds__(256, 6) void fused_kernel(
    const float* __restrict__ h, const float* __restrict__ ea,
    const unsigned int* __restrict__ hb,
    const int* __restrict__ offsets, const int2* __restrict__ perm2,
    const float* __restrict__ W1, const float* __restrict__ b1,
    const float* __restrict__ W2, const float* __restrict__ b2,
    const float* __restrict__ eps, float* __restrict__ out)
{
    __shared__ float s_lds[5120];   // 20 KB
    int2* s_perm = (int2*)s_lds;
    unsigned int* s_aggr = (unsigned int*)s_lds;            // [16][64] u32 (bf16 pairs)
    float* s_w = s_lds + 1024;                              // 2048 f32 (8 KB)
    unsigned int* s_hid = (unsigned int*)(s_lds + 3072);    // [16][128] u32 (bf16 pairs)

    const int tid = threadIdx.x;
    const int t  = tid >> 4;            // node 0..15
    const int c8 = (tid & 15) << 3;     // float col 0..120 (8 per lane)
    const int node0 = blockIdx.x * TN;
    const int blkbeg = offsets[node0];
    const int blkend = offsets[node0 + TN];
    const int nbeg = offsets[node0 + t];
    const int nend = offsets[node0 + t + 1];

    f4 a0 = (f4)(0.f);
    f4 a1 = (f4)(0.f);

    for (int cb = blkbeg; cb < blkend; cb += MAXC) {
        const int cnt = min(blkend - cb, MAXC);
        __syncthreads();   // prior chunk's s_perm reads done
        for (int i = tid; i < cnt; i += 256) s_perm[i] = perm2[cb + i];
        __syncthreads();
        const int lo = max(nbeg - cb, 0);
        const int hi = min(nend - cb, cnt);
        int j = lo;
        // main: 4 edges per iteration, 12 loads hoisted
        for (; j + 3 < hi; j += 4) {
            int2 p[4];
            #pragma unroll
            for (int q = 0; q < 4; ++q) p[q] = s_perm[j + q];
            f4 ev0[4], ev1[4];
            u4 hu[4];
            #pragma unroll
            for (int q = 0; q < 4; ++q) {
                const float* er = ea + (size_t)(unsigned)p[q].x + c8;
                ev0[q] = ldg_nt(er);
                ev1[q] = ldg_nt(er + 4);
                hu[q]  = *(const u4*)(hb + (((unsigned)p[q].y + c8) >> 1));
            }
            #pragma unroll
            for (int q = 0; q < 4; ++q) {
                f4 hv0, hv1;
                hv0[0] = bflo(hu[q].x); hv0[1] = bfhi(hu[q].x);
                hv0[2] = bflo(hu[q].y); hv0[3] = bfhi(hu[q].y);
                hv1[0] = bflo(hu[q].z); hv1[1] = bfhi(hu[q].z);
                hv1[2] = bflo(hu[q].w); hv1[3] = bfhi(hu[q].w);
                a0 += ev0[q] + hv0;
                a1 += ev1[q] + hv1;
            }
        }
        // tail: 0..3 edges
        for (; j < hi; ++j) {
            const int2 p = s_perm[j];
            const float* er = ea + (size_t)(unsigned)p.x + c8;
            const f4 e0 = ldg_nt(er);
            const f4 e1 = ldg_nt(er + 4);
            const u4 u = *(const u4*)(hb + (((unsigned)p.y + c8) >> 1));
            f4 hv0, hv1;
            hv0[0] = bflo(u.x); hv0[1] = bfhi(u.x);
            hv0[2] = bflo(u.y); hv0[3] = bfhi(u.y);
            hv1[0] = bflo(u.z); hv1[1] = bfhi(u.z);
            hv1[2] = bflo(u.w); hv1[3] = bfhi(u.w);
            a0 += e0 + hv0;
            a1 += e1 + hv1;
        }
    }
    __syncthreads();   // all s_perm reads done; LDS free for GEMM-phase layout
    {
        unsigned int* ad = s_aggr + t * 64 + (c8 >> 1);
        ad[0] = bfpair(a0[0], a0[1]);
        ad[1] = bfpair(a0[2], a0[3]);
        ad[2] = bfpair(a1[0], a1[1]);
        ad[3] = bfpair(a1[2], a1[3]);
    }
    // (aggr visibility ensured by the barrier at top of GEMM1's k-loop)

    // ---- GEMM1: hidden = relu(aggr @ W1 + b1), W1 staged in 8-row k-tiles --
    const int j0 = (tid & 63) << 2;    // 0..252
    const int tbase = (tid >> 6) << 2; // 0,4,8,12
    {
        float4 acc1[4];
        const float4 bv = *(const float4*)(b1 + j0);
        #pragma unroll
        for (int q = 0; q < 4; ++q) acc1[q] = bv;
        for (int k0 = 0; k0 < D; k0 += 8) {
            __syncthreads();  // aggr visible (first iter) / prior wtile reads done
            // stage W1[k0..k0+8][0..256] = 512 f4; 2 f4 per thread
            {
                const float4* srcw = (const float4*)(W1 + (size_t)k0 * H2);
                float4* dstl = (float4*)s_w;
                dstl[tid]       = srcw[tid];
                dstl[tid + 256] = srcw[tid + 256];
            }
            __syncthreads();
            #pragma unroll
            for (int kk = 0; kk < 8; kk += 4) {
                float4 w[4];
                #pragma unroll
                for (int q = 0; q < 4; ++q)
                    w[q] = *(const float4*)&s_w[(kk + q) * H2 + j0];
                #pragma unroll
                for (int u = 0; u < 4; ++u) {
                    const unsigned int* ar = s_aggr + (tbase + u) * 64 + ((k0 + kk) >> 1);
                    const unsigned int u01 = ar[0];
                    const unsigned int u23 = ar[1];
                    float4 a;
                    a.x = bflo(u01); a.y = bfhi(u01);
                    a.z = bflo(u23); a.w = bfhi(u23);
                    acc1[u].x = fmaf(a.x, w[0].x, acc1[u].x);
                    acc1[u].y = fmaf(a.x, w[0].y, acc1[u].y);
                    acc1[u].z = fmaf(a.x, w[0].z, acc1[u].z);
                    acc1[u].w = fmaf(a.x, w[0].w, acc1[u].w);
                    acc1[u].x = fmaf(a.y, w[1].x, acc1[u].x);
                    acc1[u].y = fmaf(a.y, w[1].y, acc1[u].y);
                    acc1[u].z = fmaf(a.y, w[1].z, acc1[u].z);
                    acc1[u].w = fmaf(a.y, w[1].w, acc1[u].w);
                    acc1[u].x = fmaf(a.z, w[2].x, acc1[u].x);
                    acc1[u].y = fmaf(a.z, w[2].y, acc1[u].y);
                    acc1[u].z = fmaf(a.z, w[2].z, acc1[u].z);
                    acc1[u].w = fmaf(a.z, w[2].w, acc1[u].w);
                    acc1[u].x = fmaf(a.w, w[3].x, acc1[u].x);
                    acc1[u].y = fmaf(a.w, w[3].y, acc1[u].y);
                    acc1[u].z = fmaf(a.w, w[3].z, acc1[u].z);
                    acc1[u].w = fmaf(a.w, w[3].w, acc1[u].w);
                }
            }
        }
        // write hidden as bf16 (region disjoint from aggr/wtile)
        #pragma unroll
        for (int u = 0; u < 4; ++u) {
            unsigned int* hd = s_hid + (tbase + u) * 128 + (j0 >> 1);
            hd[0] = bfpair(fmaxf(acc1[u].x, 0.f), fmaxf(acc1[u].y, 0.f));
            hd[1] = bfpair(fmaxf(acc1[u].z, 0.f), fmaxf(acc1[u].w, 0.f));
        }
    }

    // ---- GEMM2 + residual, W2 staged in 16-row k-tiles ----
    {
        const int i0 = (tid & 31) << 2;    // 0..124
        const int g = tid >> 5;            // 0..7 -> nodes g, g+8
        float4 acc2[2];
        const float4 bv = *(const float4*)(b2 + i0);
        acc2[0] = bv; acc2[1] = bv;
        for (int k0 = 0; k0 < H2; k0 += 16) {
            __syncthreads();  // hidden visible (first iter) / prior wtile reads done
            // stage W2[k0..k0+16][0..128] = 512 f4; 2 f4 per thread
            {
                const float4* srcw = (const float4*)(W2 + (size_t)k0 * D);
                float4* dstl = (float4*)s_w;
                dstl[tid]       = srcw[tid];
                dstl[tid + 256] = srcw[tid + 256];
            }
            __syncthreads();
            #pragma unroll
            for (int kk = 0; kk < 16; kk += 4) {
                float4 w[4];
                #pragma unroll
                for (int q = 0; q < 4; ++q)
                    w[q] = *(const float4*)&s_w[(kk + q) * D + i0];
                #pragma unroll
                for (int u = 0; u < 2; ++u) {
                    const unsigned int* hr = s_hid + (g + u * 8) * 128 + ((k0 + kk) >> 1);
                    const unsigned int u01 = hr[0];
                    const unsigned int u23 = hr[1];
                    float4 a;
                    a.x = bflo(u01); a.y = bfhi(u01);
                    a.z = bflo(u23); a.w = bfhi(u23);
                    acc2[u].x = fmaf(a.x, w[0].x, acc2[u].x);
                    acc2[u].y = fmaf(a.x, w[0].y, acc2[u].y);
                    acc2[u].z = fmaf(a.x, w[0].z, acc2[u].z);
                    acc2[u].w = fmaf(a.x, w[0].w, acc2[u].w);
                    acc2[u].x = fmaf(a.y, w[1].x, acc2[u].x);
                    acc2[u].y = fmaf(a.y, w[1].y, acc2[u].y);
                    acc2[u].z = fmaf(a.y, w[1].z, acc2[u].z);
                    acc2[u].w = fmaf(a.y, w[1].w, acc2[u].w);
                    acc2[u].x = fmaf(a.z, w[2].x, acc2[u].x);
                    acc2[u].y = fmaf(a.z, w[2].y, acc2[u].y);
                    acc2[u].z = fmaf(a.z, w[2].z, acc2[u].z);
                    acc2[u].w = fmaf(a.z, w[2].w, acc2[u].w);
                    acc2[u].x = fmaf(a.w, w[3].x, acc2[u].x);
                    acc2[u].y = fmaf(a.w, w[3].y, acc2[u].y);
                    acc2[u].z = fmaf(a.w, w[3].z, acc2[u].z);
                    acc2[u].w = fmaf(a.w, w[3].w, acc2[u].w);
                }
            }
        }
        const float ep = 1.0f + eps[0];
        #pragma unroll
        for (int u = 0; u < 2; ++u) {
            const int node = node0 + g + u * 8;
            const f4 hv = ldg(h + (size_t)node * D + i0);
            f4 o;
            o[0] = fmaf(ep, hv[0], acc2[u].x);
            o[1] = fmaf(ep, hv[1], acc2[u].y);
            o[2] = fmaf(ep, hv[2], acc2[u].z);
            o[3] = fmaf(ep, hv[3], acc2[u].w);
            __builtin_nontemporal_store(o, (f4*)(out + (size_t)node * D + i0));
        }
    }
}

extern "C" void kernel_launch(void* const* d_in, const int* in_sizes, int n_in,
                              void* d_out, int out_size, void* d_ws, size_t ws_size,
                              hipStream_t stream) {
    const float* h   = (const float*)d_in[0];
    const float* ea  = (const float*)d_in[1];
    const int*   src = (const int*)d_in[2];
    const int*   dst = (const int*)d_in[3];
    const float* W1  = (const float*)d_in[4];
    const float* b1  = (const float*)d_in[5];
    const float* W2  = (const float*)d_in[6];
    const float* b2  = (const float*)d_in[7];
    const float* eps = (const float*)d_in[8];
    float* out = (float*)d_out;

    char* ws = (char*)d_ws;
    int*  counts    = (int*)ws;                       // 200 KB
    int*  scanned   = (int*)(ws + 256 * 1024);        // 200 KB
    int*  offsets   = (int*)(ws + 512 * 1024);        // 200 KB (+1)
    int*  cursor    = (int*)(ws + 768 * 1024);        // 200 KB
    int*  blocksums = (int*)(ws + 1008 * 1024);       // 1 KB
    int*  blockbase = (int*)(ws + 1012 * 1024);       // 1 KB
    int2* perm2     = (int2*)(ws + 1024 * 1024);      // 4.8 MB
    unsigned int* hbm = (unsigned int*)(ws + 6 * 1024 * 1024);  // 12.8 MB bf16 h

    hipMemsetAsync(counts, 0, N_NODES * sizeof(int), stream);

    const int eblocks = (N_EDGES + 255) / 256;     // 2344
    const int nblocks = (N_NODES + 255) / 256;     // 196

    hcvt_kernel<<<(N_NODES * D / 8 + 255) / 256, 256, 0, stream>>>(h, (u4*)hbm);
    hist_kernel<<<eblocks, 256, 0, stream>>>(dst, counts);
    scan1_kernel<<<nblocks, 256, 0, stream>>>(counts, scanned, blocksums);
    scan2_kernel<<<1, 256, 0, stream>>>(blocksums, blockbase, nblocks);
    scan3_kernel<<<nblocks, 256, 0, stream>>>(scanned, blockbase, offsets, cursor);
    scatter_kernel<<<eblocks, 256, 0, stream>>>(src, dst, cursor, perm2);
    fused_kernel<<<N_NODES / TN, 256, 0, stream>>>(
        h, ea, hbm, offsets, perm2, W1, b1, W2, b2, eps, out);
}

// Round 9
// 549.617 us; speedup vs baseline: 1.5740x; 1.0609x over previous
//
#include <hip/hip_runtime.h>

#define N_NODES 50000
#define N_EDGES 600000
#define D 128
#define H2 256
#define TN 16      // nodes per fused block (50000/16 = 3125 exactly)
#define MAXC 2048  // perm chunk capacity in LDS (16KB <= 20KB region)

typedef float f4 __attribute__((ext_vector_type(4)));
typedef unsigned int u4 __attribute__((ext_vector_type(4)));
typedef short s8v __attribute__((ext_vector_type(8)));   // 8 bf16 (4 VGPRs)

__device__ __forceinline__ f4 ldg_nt(const float* p) {
    return __builtin_nontemporal_load((const f4*)p);
}
__device__ __forceinline__ f4 ldg(const float* p) {
    return *(const f4*)p;
}

// pack two f32 -> one u32 of 2x bf16 (round-to-nearest-even)
__device__ __forceinline__ unsigned int bfpair(float lo, float hi) {
    unsigned int ul = __float_as_uint(lo), uh = __float_as_uint(hi);
    ul += 0x7FFFu + ((ul >> 16) & 1u);
    uh += 0x7FFFu + ((uh >> 16) & 1u);
    return (ul >> 16) | (uh & 0xFFFF0000u);
}
__device__ __forceinline__ unsigned short bf16of(float v) {
    unsigned int u = __float_as_uint(v);
    u += 0x7FFFu + ((u >> 16) & 1u);
    return (unsigned short)(u >> 16);
}
__device__ __forceinline__ float bflo(unsigned int u) { return __uint_as_float(u << 16); }
__device__ __forceinline__ float bfhi(unsigned int u) { return __uint_as_float(u & 0xFFFF0000u); }

// ---------------------------------------------------------------------------
// Stage 0a: h -> bf16 mirror (for the x12-reused gather operand only).
__global__ __launch_bounds__(256) void hcvt_kernel(const float* __restrict__ h,
                                                   u4* __restrict__ hb4) {
    const int i = blockIdx.x * 256 + threadIdx.x;
    if (i < (N_NODES * D) / 8) {
        const f4 v0 = ldg(h + (size_t)i * 8);
        const f4 v1 = ldg(h + (size_t)i * 8 + 4);
        u4 o;
        o.x = bfpair(v0[0], v0[1]);
        o.y = bfpair(v0[2], v0[3]);
        o.z = bfpair(v1[0], v1[1]);
        o.w = bfpair(v1[2], v1[3]);
        hb4[i] = o;
    }
}

// Stage 0b: W1[k][n] -> W1t bf16 [n][k] (u32 = 2 consecutive k), same for W2.
// W1t: 256n x 64kp u32 = 16384; W2t: 128n x 128kp = 16384. 128 blocks x 256.
__global__ __launch_bounds__(256) void wcvt_kernel(const float* __restrict__ W1,
                                                   const float* __restrict__ W2,
                                                   unsigned int* __restrict__ w1t,
                                                   unsigned int* __restrict__ w2t) {
    const int tid = blockIdx.x * 256 + threadIdx.x;
    if (tid < 256 * 64) {
        const int n = tid >> 6, kp = tid & 63;
        w1t[tid] = bfpair(W1[(size_t)(2 * kp) * H2 + n], W1[(size_t)(2 * kp + 1) * H2 + n]);
    } else if (tid < 256 * 64 + 128 * 128) {
        const int t2 = tid - 256 * 64;
        const int n = t2 >> 7, kp = t2 & 127;
        w2t[t2] = bfpair(W2[(size_t)(2 * kp) * D + n], W2[(size_t)(2 * kp + 1) * D + n]);
    }
}

// ---------------------------------------------------------------------------
// Stage 1: histogram of dst -> counts[50000]
__global__ __launch_bounds__(256) void hist_kernel(const int* __restrict__ dst,
                                                   int* __restrict__ counts) {
    unsigned int e = blockIdx.x * 256u + threadIdx.x;
    if (e < N_EDGES) atomicAdd(&counts[dst[e]], 1);
}

// Stage 2a: block-local exclusive scan (196 blocks x 256 threads)
__global__ __launch_bounds__(256) void scan1_kernel(const int* __restrict__ counts,
                                                    int* __restrict__ scanned,
                                                    int* __restrict__ blocksums) {
    __shared__ int wsum[4];
    const int tid = threadIdx.x;
    const int lane = tid & 63;
    const int wv = tid >> 6;
    const int i = blockIdx.x * 256 + tid;
    const int cval = (i < N_NODES) ? counts[i] : 0;
    int x = cval;
    #pragma unroll
    for (int d = 1; d < 64; d <<= 1) {
        int t = __shfl_up(x, d, 64);
        if (lane >= d) x += t;
    }
    if (lane == 63) wsum[wv] = x;
    __syncthreads();
    if (tid == 0) {
        int s = 0;
        #pragma unroll
        for (int w = 0; w < 4; ++w) { s += wsum[w]; wsum[w] = s; }
    }
    __syncthreads();
    const int prefix = (wv > 0 ? wsum[wv - 1] : 0) + (x - cval);
    if (i < N_NODES) scanned[i] = prefix;
    if (tid == 0) blocksums[blockIdx.x] = wsum[3];
}

// Stage 2b: exclusive scan of the 196 block sums (1 block, 256 threads)
__global__ __launch_bounds__(256) void scan2_kernel(const int* __restrict__ blocksums,
                                                    int* __restrict__ blockbase, int nb) {
    __shared__ int wsum[4];
    const int tid = threadIdx.x;
    const int lane = tid & 63;
    const int wv = tid >> 6;
    const int cval = (tid < nb) ? blocksums[tid] : 0;
    int x = cval;
    #pragma unroll
    for (int d = 1; d < 64; d <<= 1) {
        int t = __shfl_up(x, d, 64);
        if (lane >= d) x += t;
    }
    if (lane == 63) wsum[wv] = x;
    __syncthreads();
    if (tid == 0) {
        int s = 0;
        #pragma unroll
        for (int w = 0; w < 4; ++w) { s += wsum[w]; wsum[w] = s; }
    }
    __syncthreads();
    if (tid < nb) blockbase[tid] = (wv > 0 ? wsum[wv - 1] : 0) + (x - cval);
}

// Stage 2c: add block bases -> offsets, prime cursor
__global__ __launch_bounds__(256) void scan3_kernel(const int* __restrict__ scanned,
                                                    const int* __restrict__ blockbase,
                                                    int* __restrict__ offsets,
                                                    int* __restrict__ cursor) {
    const int i = blockIdx.x * 256 + threadIdx.x;
    if (i < N_NODES) {
        const int v = scanned[i] + blockbase[blockIdx.x];
        offsets[i] = v;
        cursor[i] = v;
    }
    if (i == 0) offsets[N_NODES] = N_EDGES;
}

// Stage 3: scatter edges into dst-sorted order.
// perm2[p] = (e*D, src*D)  -- premultiplied element offsets (fit in int32).
__global__ __launch_bounds__(256) void scatter_kernel(const int* __restrict__ src,
                                                      const int* __restrict__ dst,
                                                      int* __restrict__ cursor,
                                                      int2* __restrict__ perm2) {
    unsigned int e = blockIdx.x * 256u + threadIdx.x;
    if (e >= N_EDGES) return;
    const int d = dst[e];
    const int p = atomicAdd(&cursor[d], 1);
    perm2[p] = make_int2((int)(e * D), src[e] * D);
}

// ---------------------------------------------------------------------------
// Stage 4: fused gather + MFMA MLP + residual. Block = 16 nodes, 256 threads.
// Gather: unchanged from round 8 (ea f32 NT x2 + h bf16 mirror x1 per edge).
// MLP: mfma_f32_16x16x32_bf16. A-operands (aggr/hidden bf16) live in LDS with
// XOR swizzle (u32idx ^= (row&7)<<2) for bank-balanced ds_read_b128; B-operands
// are contiguous 16B loads from pre-transposed bf16 W in global (L2-resident,
// no LDS staging, no k-tile barriers). GEMM2 result staged via 8KB LDS f32
// tile so the epilogue keeps coalesced f4 h/b2 reads + NT stores.
// LDS 20 KB: aggr u32[0,4K)B | hidden u32[4K,12K)B | outF f32[12K,20K)B.
// s_perm (16KB) aliases [0,16K) during gather (dead before aggr write).
__global__ __launch_bounds__(256, 6) void fused_kernel(
    const float* __restrict__ h, const float* __restrict__ ea,
    const unsigned int* __restrict__ hb,
    const unsigned short* __restrict__ w1t, const unsigned short* __restrict__ w2t,
    const int* __restrict__ offsets, const int2* __restrict__ perm2,
    const float* __restrict__ b1, const float* __restrict__ b2,
    const float* __restrict__ eps, float* __restrict__ out)
{
    __shared__ float s_lds[5120];   // 20 KB
    int2* s_perm = (int2*)s_lds;
    unsigned int* s_aggrU = (unsigned int*)s_lds;            // [16][64] u32 (bf16 pairs)
    unsigned int* s_hidU  = (unsigned int*)(s_lds + 1024);   // [16][128] u32 (bf16 pairs)
    unsigned short* s_hid16 = (unsigned short*)(s_lds + 1024);
    float* s_outF = s_lds + 3072;                            // [16][128] f32

    const int tid = threadIdx.x;
    const int t  = tid >> 4;            // node 0..15
    const int c8 = (tid & 15) << 3;     // float col 0..120 (8 per lane)
    const int node0 = blockIdx.x * TN;
    const int blkbeg = offsets[node0];
    const int blkend = offsets[node0 + TN];
    const int nbeg = offsets[node0 + t];
    const int nend = offsets[node0 + t + 1];

    f4 a0 = (f4)(0.f);
    f4 a1 = (f4)(0.f);

    for (int cb = blkbeg; cb < blkend; cb += MAXC) {
        const int cnt = min(blkend - cb, MAXC);
        __syncthreads();   // prior chunk's s_perm reads done
        for (int i = tid; i < cnt; i += 256) s_perm[i] = perm2[cb + i];
        __syncthreads();
        const int lo = max(nbeg - cb, 0);
        const int hi = min(nend - cb, cnt);
        int j = lo;
        // main: 4 edges per iteration, 12 loads hoisted
        for (; j + 3 < hi; j += 4) {
            int2 p[4];
            #pragma unroll
            for (int q = 0; q < 4; ++q) p[q] = s_perm[j + q];
            f4 ev0[4], ev1[4];
            u4 hu[4];
            #pragma unroll
            for (int q = 0; q < 4; ++q) {
                const float* er = ea + (size_t)(unsigned)p[q].x + c8;
                ev0[q] = ldg_nt(er);
                ev1[q] = ldg_nt(er + 4);
                hu[q]  = *(const u4*)(hb + (((unsigned)p[q].y + c8) >> 1));
            }
            #pragma unroll
            for (int q = 0; q < 4; ++q) {
                f4 hv0, hv1;
                hv0[0] = bflo(hu[q].x); hv0[1] = bfhi(hu[q].x);
                hv0[2] = bflo(hu[q].y); hv0[3] = bfhi(hu[q].y);
                hv1[0] = bflo(hu[q].z); hv1[1] = bfhi(hu[q].z);
                hv1[2] = bflo(hu[q].w); hv1[3] = bfhi(hu[q].w);
                a0 += ev0[q] + hv0;
                a1 += ev1[q] + hv1;
            }
        }
        // tail: 0..3 edges
        for (; j < hi; ++j) {
            const int2 p = s_perm[j];
            const float* er = ea + (size_t)(unsigned)p.x + c8;
            const f4 e0 = ldg_nt(er);
            const f4 e1 = ldg_nt(er + 4);
            const u4 u = *(const u4*)(hb + (((unsigned)p.y + c8) >> 1));
            f4 hv0, hv1;
            hv0[0] = bflo(u.x); hv0[1] = bfhi(u.x);
            hv0[2] = bflo(u.y); hv0[3] = bfhi(u.y);
            hv1[0] = bflo(u.z); hv1[1] = bfhi(u.z);
            hv1[2] = bflo(u.w); hv1[3] = bfhi(u.w);
            a0 += e0 + hv0;
            a1 += e1 + hv1;
        }
    }
    __syncthreads();   // all s_perm reads done; LDS free for GEMM-phase layout
    {
        // aggr write: u32 idx = t*64 + (tid&15)*4, XOR-swizzled by row.
        // XOR bits 2..4 keep the 4 consecutive u32 contiguous (one b128 write).
        u4 av;
        av.x = bfpair(a0[0], a0[1]);
        av.y = bfpair(a0[2], a0[3]);
        av.z = bfpair(a1[0], a1[1]);
        av.w = bfpair(a1[2], a1[3]);
        const int ai = (t * 64 + ((tid & 15) << 2)) ^ ((t & 7) << 2);
        *(u4*)(s_aggrU + ai) = av;
    }
    __syncthreads();   // aggr visible to all waves

    const int lane = tid & 63;
    const int wid = tid >> 6;          // wave 0..3
    const int r = lane & 15;           // col-of-tile / row-of-A
    const int g = lane >> 4;           // 0..3 k-subslice / D-row group

    // ---- GEMM1 (MFMA): hidden = relu(aggr @ W1 + b1) ----
    {
        s8v afr[4];
        #pragma unroll
        for (int ks = 0; ks < 4; ++ks)
            afr[ks] = *(const s8v*)(s_aggrU + ((r * 64 + ks * 16 + g * 4) ^ ((r & 7) << 2)));
        #pragma unroll
        for (int i = 0; i < 4; ++i) {
            const int n0 = (wid * 4 + i) * 16;
            f4 acc = (f4)(0.f);
            #pragma unroll
            for (int ks = 0; ks < 4; ++ks) {
                const s8v bfr = *(const s8v*)(w1t + (size_t)(n0 + r) * 128 + ks * 32 + g * 8);
                acc = __builtin_amdgcn_mfma_f32_16x16x32_bf16(afr[ks], bfr, acc, 0, 0, 0);
            }
            const int c = n0 + r;
            const float b1c = b1[c];
            #pragma unroll
            for (int reg = 0; reg < 4; ++reg) {
                const int rd = g * 4 + reg;
                const float v = fmaxf(acc[reg] + b1c, 0.f);
                const int ui = (rd * 128 + (c >> 1)) ^ ((rd & 7) << 2);
                s_hid16[ui * 2 + (c & 1)] = bf16of(v);
            }
        }
    }
    __syncthreads();   // hidden complete

    // ---- GEMM2 (MFMA): outF = hidden @ W2 ----
    {
        s8v hfr[8];
        #pragma unroll
        for (int ks = 0; ks < 8; ++ks)
            hfr[ks] = *(const s8v*)(s_hidU + ((r * 128 + ks * 16 + g * 4) ^ ((r & 7) << 2)));
        #pragma unroll
        for (int i = 0; i < 2; ++i) {
            const int n0 = (wid * 2 + i) * 16;
            f4 acc = (f4)(0.f);
            #pragma unroll
            for (int ks = 0; ks < 8; ++ks) {
                const s8v bfr = *(const s8v*)(w2t + (size_t)(n0 + r) * 256 + ks * 32 + g * 8);
                acc = __builtin_amdgcn_mfma_f32_16x16x32_bf16(hfr[ks], bfr, acc, 0, 0, 0);
            }
            #pragma unroll
            for (int reg = 0; reg < 4; ++reg)
                s_outF[(g * 4 + reg) * 128 + n0 + r] = acc[reg];
        }
    }
    __syncthreads();   // outF complete

    // ---- epilogue: out = outF + b2 + (1+eps)*h  (coalesced f4 IO) ----
    {
        const int i0 = (tid & 31) << 2;    // 0..124
        const int gg = tid >> 5;           // 0..7 -> nodes gg, gg+8
        const float ep = 1.0f + eps[0];
        const f4 b2v = ldg(b2 + i0);
        #pragma unroll
        for (int u = 0; u < 2; ++u) {
            const int nl = gg + u * 8;
            const int node = node0 + nl;
            const f4 sv = *(const f4*)&s_outF[nl * 128 + i0];
            const f4 hv = ldg(h + (size_t)node * D + i0);
            f4 o;
            o[0] = sv[0] + b2v[0] + ep * hv[0];
            o[1] = sv[1] + b2v[1] + ep * hv[1];
            o[2] = sv[2] + b2v[2] + ep * hv[2];
            o[3] = sv[3] + b2v[3] + ep * hv[3];
            __builtin_nontemporal_store(o, (f4*)(out + (size_t)node * D + i0));
        }
    }
}

extern "C" void kernel_launch(void* const* d_in, const int* in_sizes, int n_in,
                              void* d_out, int out_size, void* d_ws, size_t ws_size,
                              hipStream_t stream) {
    const float* h   = (const float*)d_in[0];
    const float* ea  = (const float*)d_in[1];
    const int*   src = (const int*)d_in[2];
    const int*   dst = (const int*)d_in[3];
    const float* W1  = (const float*)d_in[4];
    const float* b1  = (const float*)d_in[5];
    const float* W2  = (const float*)d_in[6];
    const float* b2  = (const float*)d_in[7];
    const float* eps = (const float*)d_in[8];
    float* out = (float*)d_out;

    char* ws = (char*)d_ws;
    int*  counts    = (int*)ws;                       // 200 KB
    int*  scanned   = (int*)(ws + 256 * 1024);        // 200 KB
    int*  offsets   = (int*)(ws + 512 * 1024);        // 200 KB (+1)
    int*  cursor    = (int*)(ws + 768 * 1024);        // 200 KB
    int*  blocksums = (int*)(ws + 1008 * 1024);       // 1 KB
    int*  blockbase = (int*)(ws + 1012 * 1024);       // 1 KB
    int2* perm2     = (int2*)(ws + 1024 * 1024);      // 4.8 MB
    unsigned int* hbm = (unsigned int*)(ws + 6 * 1024 * 1024);    // 12.8 MB bf16 h
    unsigned int* w1t = (unsigned int*)(ws + 20 * 1024 * 1024);   // 64 KB
    unsigned int* w2t = (unsigned int*)(ws + 21 * 1024 * 1024);   // 64 KB

    hipMemsetAsync(counts, 0, N_NODES * sizeof(int), stream);

    const int eblocks = (N_EDGES + 255) / 256;     // 2344
    const int nblocks = (N_NODES + 255) / 256;     // 196

    hcvt_kernel<<<(N_NODES * D / 8 + 255) / 256, 256, 0, stream>>>(h, (u4*)hbm);
    wcvt_kernel<<<128, 256, 0, stream>>>(W1, W2, w1t, w2t);
    hist_kernel<<<eblocks, 256, 0, stream>>>(dst, counts);
    scan1_kernel<<<nblocks, 256, 0, stream>>>(counts, scanned, blocksums);
    scan2_kernel<<<1, 256, 0, stream>>>(blocksums, blockbase, nblocks);
    scan3_kernel<<<nblocks, 256, 0, stream>>>(scanned, blockbase, offsets, cursor);
    scatter_kernel<<<eblocks, 256, 0, stream>>>(src, dst, cursor, perm2);
    fused_kernel<<<N_NODES / TN, 256, 0, stream>>>(
        h, ea, hbm, (const unsigned short*)w1t, (const unsigned short*)w2t,
        offsets, perm2, b1, b2, eps, out);
}